// Round 13
// baseline (935.651 us; speedup 1.0000x reference)
//
#include <hip/hip_runtime.h>
#include <hip/hip_bf16.h>
#include <math.h>

// Problem constants
#define NB    8
#define NC    64
#define HWP   4096          // H*W
#define HCH   2048
#define NSAMP 8388608       // HC*H*W per sample
#define KSEL  167772u       // int(0.02 * NSAMP)
#define RECON_N 2097152     // B*C*H*W
#define CAND_CAP 524288u    // per-sample candidate entries (uint2 = 8B) -> 4MB/sample
#define CBUF_CAP 1536u      // per-block LDS candidate buffer (exp ~400/block)
#define BUCK_CAP 512        // per-(b,p) bucket capacity (mean 41, +73 sigma)

// Workspace layout (bytes)
#define WS_CAND   0u          // 8 * 524288 * 8 = 33554432
#define WS_WD     33554432u   // wd bf16: 131072 * 2
#define WS_GHIST  33816576u   // 8*2048*4 = 65536
#define WS_MID    33882112u   // 8*1024*4 = 32768
#define WS_LOW    33914880u   // 8*1024*4 = 32768
#define WS_PART   33947648u   // 8*512*2*8 doubles = 65536 (region holds 262144)
#define WS_NORM   34209792u
#define WS_BETA   34210048u
#define WS_BINT0  34210080u
#define WS_C1     34210112u
#define WS_REM    34210144u
#define WS_C2     34210176u
#define WS_REM2   34210208u
#define WS_KTH    34210240u
#define WS_FLAGS  34210304u   // 8*4 (bit0: hist insufficiency, bit1: cand overflow)
#define WS_GCNT   34210432u   // 8 counters padded 128B = 1024
#define WS_BCNT   34211456u   // 8*4096*4 = 131072 bucket counts -> ends 34342528

__device__ __forceinline__ unsigned bf16r(float f) {   // RNE round to bf16
  unsigned u = __float_as_uint(f);
  unsigned r = (u >> 16) & 1u;
  return (u + 0x7fffu + r) >> 16;
}

// ---------------- K0a: decoder column norms ----------------
__global__ __launch_bounds__(256) void k0a_norm(const float* __restrict__ W,
                                                float* __restrict__ normv) {
  __shared__ float red[256];
  int c = blockIdx.x, t = threadIdx.x;
  float s = 0.f;
  for (int o = t; o < HCH; o += 256) { float w = W[o * NC + c]; s += w * w; }
  red[t] = s; __syncthreads();
  for (int off = 128; off; off >>= 1) { if (t < off) red[t] += red[t + off]; __syncthreads(); }
  if (t == 0) normv[c] = fmaxf(sqrtf(red[0]), 1e-12f);
}

// ---------------- K0b: wdb[o][c] = bf16(W[o][c] / norm[c]) ----------------
__global__ __launch_bounds__(256) void k0b_wd(const float* __restrict__ W,
                                              const float* __restrict__ normv,
                                              unsigned short* __restrict__ wdb) {
  int i = blockIdx.x * 256 + threadIdx.x;
  if (i < HCH * NC) wdb[i] = (unsigned short)bf16r(W[i] / normv[i & 63]);
}

// ---------------- K1: encode GEMM (128x128 tile, 8x8 micro) + sum/sumsq ----------------
__global__ __launch_bounds__(256) void k1_encode(const float* __restrict__ x,
                                                 const float* __restrict__ W,
                                                 const float* __restrict__ b_enc,
                                                 const float* __restrict__ b_dec,
                                                 float* __restrict__ pre,
                                                 double* __restrict__ part) {
  __shared__ float xs[64][128];   // [c][p]
  __shared__ float wt[64][128];   // [c][o]
  const int t = threadIdx.x;
  const int pt = blockIdx.x;      // 0..31
  const int ot = blockIdx.y;      // 0..15
  const int b  = blockIdx.z;
  const int p0 = pt << 7, o0 = ot << 7;

  {
    const int c  = t >> 2;
    const int pc = (t & 3) << 5;
    const float* xp = x + (((size_t)(b * NC + c)) << 12) + p0 + pc;
    const float bd = b_dec[c];
    #pragma unroll
    for (int j = 0; j < 8; j++) {
      float4 v = ((const float4*)xp)[j];
      v.x -= bd; v.y -= bd; v.z -= bd; v.w -= bd;
      *(float4*)&xs[c][pc + 4 * j] = v;
    }
    const int ol = t >> 1;
    const int c0 = (t & 1) << 5;
    const float* wp = W + (((size_t)(o0 + ol)) << 6) + c0;
    #pragma unroll
    for (int j = 0; j < 8; j++) {
      float4 w4 = ((const float4*)wp)[j];
      wt[c0 + 4 * j + 0][ol] = w4.x;
      wt[c0 + 4 * j + 1][ol] = w4.y;
      wt[c0 + 4 * j + 2][ol] = w4.z;
      wt[c0 + 4 * j + 3][ol] = w4.w;
    }
  }
  __syncthreads();

  const int og = (t >> 4) << 3;
  const int pg = (t & 15) << 3;
  float acc[8][8];
  #pragma unroll
  for (int i = 0; i < 8; i++)
    #pragma unroll
    for (int j = 0; j < 8; j++) acc[i][j] = 0.f;

  #pragma unroll 8
  for (int cc = 0; cc < 64; cc++) {
    float4 w0 = *(const float4*)&wt[cc][og];
    float4 w1 = *(const float4*)&wt[cc][og + 4];
    float4 x0 = *(const float4*)&xs[cc][pg];
    float4 x1 = *(const float4*)&xs[cc][pg + 4];
    float wv[8] = {w0.x, w0.y, w0.z, w0.w, w1.x, w1.y, w1.z, w1.w};
    float xv[8] = {x0.x, x0.y, x0.z, x0.w, x1.x, x1.y, x1.z, x1.w};
    #pragma unroll
    for (int i = 0; i < 8; i++)
      #pragma unroll
      for (int j = 0; j < 8; j++)
        acc[i][j] += wv[i] * xv[j];
  }

  double s = 0.0, s2 = 0.0;
  #pragma unroll
  for (int i = 0; i < 8; i++) {
    const float be = b_enc[o0 + og + i];
    float r[8];
    #pragma unroll
    for (int j = 0; j < 8; j++) {
      r[j] = acc[i][j] + be;
      double d = (double)r[j];
      s += d; s2 += d * d;
    }
    float* pp = pre + (((size_t)(b * HCH + o0 + og + i)) << 12) + p0 + pg;
    *(float4*)pp       = make_float4(r[0], r[1], r[2], r[3]);
    *(float4*)(pp + 4) = make_float4(r[4], r[5], r[6], r[7]);
  }
  #pragma unroll
  for (int off = 32; off; off >>= 1) { s += __shfl_down(s, off); s2 += __shfl_down(s2, off); }
  __syncthreads();
  double* redd = (double*)&xs[0][0];
  if ((t & 63) == 0) { redd[(t >> 6) * 2] = s; redd[(t >> 6) * 2 + 1] = s2; }
  __syncthreads();
  if (t == 0) {
    double ts = redd[0] + redd[2] + redd[4] + redd[6];
    double t2 = redd[1] + redd[3] + redd[5] + redd[7];
    int pidx = (b * 16 + ot) * 32 + pt;
    part[2 * pidx] = ts; part[2 * pidx + 1] = t2;
  }
}

// ---------------- K2: reduce -> beta, binT0 (3.0*beta) ----------------
__global__ __launch_bounds__(256) void k2_beta(const double* __restrict__ part,
                                               float* __restrict__ beta,
                                               unsigned* __restrict__ binT0) {
  __shared__ double sd[256], sd2[256];
  int b = blockIdx.x, t = threadIdx.x;
  double s = 0.0, s2 = 0.0;
  for (int j = 0; j < 2; j++) {
    int pi = b * 512 + t * 2 + j;
    s += part[2 * pi]; s2 += part[2 * pi + 1];
  }
  sd[t] = s; sd2[t] = s2; __syncthreads();
  for (int off = 128; off; off >>= 1) {
    if (t < off) { sd[t] += sd[t + off]; sd2[t] += sd2[t + off]; }
    __syncthreads();
  }
  if (t == 0) {
    const double n = (double)NSAMP;
    double var = (sd2[0] - sd[0] * sd[0] / n) / (n - 1.0);
    if (var < 0.0) var = 0.0;
    float bv = (float)(sqrt(var) * 10.000001);
    beta[b] = bv;
    binT0[b] = __float_as_uint(3.0f * bv) >> 20;
  }
}

// ---------------- K3: hist + (val,idx) candidate compaction; NO acts write ----------------
__global__ __launch_bounds__(256) void k3_acts(const float* __restrict__ pre,
                                               const float* __restrict__ gum,
                                               const float* __restrict__ beta,
                                               const unsigned* __restrict__ binT0,
                                               unsigned* __restrict__ ghist,
                                               uint2* __restrict__ cand,
                                               unsigned* __restrict__ gcnt,
                                               unsigned* __restrict__ flags) {
  __shared__ unsigned lh[2048];
  __shared__ uint2 cbuf[CBUF_CAP];
  __shared__ unsigned lcnt, gbase;
  const int b = blockIdx.z;
  const float be = beta[b];
  const unsigned bT0 = binT0[b];
  const int lane = threadIdx.x & 63;
  const unsigned long long lm_lt = (1ull << lane) - 1ull;
  for (int i = threadIdx.x; i < 2048; i += 256) lh[i] = 0u;
  if (threadIdx.x == 0) lcnt = 0u;
  __syncthreads();
  const float4* p4 = (const float4*)(pre + ((size_t)b << 23));
  const float4* g4 = (const float4*)(gum + ((size_t)b << 23));
  const int per4 = 1 << 21;
  for (int i = blockIdx.x * 256 + threadIdx.x; i < per4; i += gridDim.x * 256) {
    float4 p = p4[i];
    float4 g = g4[i];
    float4 a;
    a.x = fmaxf(__fadd_rn(p.x, __fmul_rn(be, g.x)), 0.f);
    a.y = fmaxf(__fadd_rn(p.y, __fmul_rn(be, g.y)), 0.f);
    a.z = fmaxf(__fadd_rn(p.z, __fmul_rn(be, g.z)), 0.f);
    a.w = fmaxf(__fadd_rn(p.w, __fmul_rn(be, g.w)), 0.f);
    unsigned u0 = __float_as_uint(a.x), u1 = __float_as_uint(a.y);
    unsigned u2 = __float_as_uint(a.z), u3 = __float_as_uint(a.w);
    bool c0 = (a.x > 0.f) && ((u0 >> 20) >= bT0);
    bool c1 = (a.y > 0.f) && ((u1 >> 20) >= bT0);
    bool c2 = (a.z > 0.f) && ((u2 >> 20) >= bT0);
    bool c3 = (a.w > 0.f) && ((u3 >> 20) >= bT0);
    unsigned long long m0 = __ballot(c0), m1 = __ballot(c1);
    unsigned long long m2 = __ballot(c2), m3 = __ballot(c3);
    unsigned n0 = __popcll(m0), n1 = __popcll(m1), n2 = __popcll(m2), n3 = __popcll(m3);
    unsigned tot = n0 + n1 + n2 + n3;
    if (tot) {
      unsigned base = 0;
      if (lane == 0) base = atomicAdd(&lcnt, tot);
      base = (unsigned)__shfl((int)base, 0);
      unsigned i0 = base + __popcll(m0 & lm_lt);
      unsigned i1 = base + n0 + __popcll(m1 & lm_lt);
      unsigned i2 = base + n0 + n1 + __popcll(m2 & lm_lt);
      unsigned i3 = base + n0 + n1 + n2 + __popcll(m3 & lm_lt);
      const unsigned ib = ((unsigned)i) << 2;
      if (c0 && i0 < CBUF_CAP) cbuf[i0] = make_uint2(u0, ib | 0u);
      if (c1 && i1 < CBUF_CAP) cbuf[i1] = make_uint2(u1, ib | 1u);
      if (c2 && i2 < CBUF_CAP) cbuf[i2] = make_uint2(u2, ib | 2u);
      if (c3 && i3 < CBUF_CAP) cbuf[i3] = make_uint2(u3, ib | 3u);
      if (c0) atomicAdd(&lh[u0 >> 20], 1u);
      if (c1) atomicAdd(&lh[u1 >> 20], 1u);
      if (c2) atomicAdd(&lh[u2 >> 20], 1u);
      if (c3) atomicAdd(&lh[u3 >> 20], 1u);
    }
  }
  __syncthreads();
  if (threadIdx.x == 0) {
    unsigned n = lcnt;
    if (n > CBUF_CAP) { atomicOr(&flags[b], 2u); n = CBUF_CAP; }
    unsigned gb = atomicAdd(&gcnt[b * 32], n);
    if (gb + n > CAND_CAP) atomicOr(&flags[b], 2u);
    gbase = gb;
  }
  __syncthreads();
  {
    uint2* candb = cand + ((size_t)b * CAND_CAP);
    const unsigned n = (lcnt > CBUF_CAP) ? CBUF_CAP : lcnt;
    const unsigned gb = gbase;
    for (unsigned i = threadIdx.x; i < n; i += 256) {
      unsigned d = gb + i;
      if (d < CAND_CAP) candb[d] = cbuf[i];
    }
  }
  for (int i = threadIdx.x; i < 2048; i += 256) {
    unsigned v = lh[i];
    if (v) atomicAdd(&ghist[(b << 11) + i], v);
  }
}

// ---------------- K4a: restricted-hist sufficiency ----------------
__global__ __launch_bounds__(256) void k4a_check(const unsigned* __restrict__ ghist,
                                                 unsigned* __restrict__ flags) {
  __shared__ unsigned red[256];
  int b = blockIdx.x, t = threadIdx.x;
  unsigned s = 0;
  for (int j = 0; j < 8; j++) s += ghist[(b << 11) + t * 8 + j];
  red[t] = s; __syncthreads();
  for (int off = 128; off; off >>= 1) { if (t < off) red[t] += red[t + off]; __syncthreads(); }
  if (t == 0 && red[0] < KSEL) atomicOr(&flags[b], 1u);
}

// ---------------- K3fb: fallback low-bin histogram (recompute acts) ----------------
__global__ __launch_bounds__(256) void k3fb(const float* __restrict__ pre,
                                            const float* __restrict__ gum,
                                            const float* __restrict__ beta,
                                            const unsigned* __restrict__ binT0,
                                            const unsigned* __restrict__ flags,
                                            unsigned* __restrict__ ghist) {
  const int b = blockIdx.z;
  if ((flags[b] & 1u) == 0u) return;
  __shared__ unsigned lh[8192];
  const float be = beta[b];
  const unsigned bT0 = binT0[b];
  const unsigned sub = threadIdx.x & 3;
  for (int i = threadIdx.x; i < 8192; i += 256) lh[i] = 0u;
  __syncthreads();
  const float4* p4 = (const float4*)(pre + ((size_t)b << 23));
  const float4* g4 = (const float4*)(gum + ((size_t)b << 23));
  for (int i = blockIdx.x * 256 + threadIdx.x; i < (1 << 21); i += gridDim.x * 256) {
    float4 p = p4[i];
    float4 g = g4[i];
    float av[4];
    av[0] = fmaxf(__fadd_rn(p.x, __fmul_rn(be, g.x)), 0.f);
    av[1] = fmaxf(__fadd_rn(p.y, __fmul_rn(be, g.y)), 0.f);
    av[2] = fmaxf(__fadd_rn(p.z, __fmul_rn(be, g.z)), 0.f);
    av[3] = fmaxf(__fadd_rn(p.w, __fmul_rn(be, g.w)), 0.f);
    #pragma unroll
    for (int j = 0; j < 4; j++) {
      unsigned u = __float_as_uint(av[j]);
      if (av[j] > 0.f && (u >> 20) < bT0) atomicAdd(&lh[((u >> 20) << 2) | sub], 1u);
    }
  }
  __syncthreads();
  for (int i = threadIdx.x; i < 2048; i += 256) {
    unsigned v = lh[4 * i] + lh[4 * i + 1] + lh[4 * i + 2] + lh[4 * i + 3];
    if (v) atomicAdd(&ghist[(b << 11) + i], v);
  }
}

// ---------------- K4: pick coarse bin ----------------
__global__ __launch_bounds__(256) void k4_coarse(const unsigned* __restrict__ ghist,
                                                 int* __restrict__ c1v,
                                                 int* __restrict__ remv,
                                                 float* __restrict__ kth) {
  __shared__ unsigned h[2048];
  __shared__ unsigned csum[256];
  int b = blockIdx.x, t = threadIdx.x;
  for (int i = t; i < 2048; i += 256) h[i] = ghist[(b << 11) + i];
  __syncthreads();
  unsigned cs = 0;
  for (int j = 0; j < 8; j++) cs += h[t * 8 + j];
  csum[t] = cs; __syncthreads();
  unsigned suf = 0;
  for (int tt = t + 1; tt < 256; tt++) suf += csum[tt];
  if (suf < KSEL && suf + cs >= KSEL) {
    unsigned cum = suf;
    for (int j = 7; j >= 0; j--) {
      unsigned hv = h[t * 8 + j];
      cum += hv;
      if (cum >= KSEL) { c1v[b] = t * 8 + j; remv[b] = (int)(KSEL - (cum - hv)); break; }
    }
  }
  if (t == 0) {
    unsigned tot = 0;
    for (int tt = 0; tt < 256; tt++) tot += csum[tt];
    if (tot < KSEL) { c1v[b] = -1; kth[b] = 0.f; }
  }
}

// ---------------- K5m: mid histogram within c1 ----------------
__global__ __launch_bounds__(256) void k5m(const float* __restrict__ pre,
                                           const float* __restrict__ gum,
                                           const float* __restrict__ beta,
                                           const uint2* __restrict__ cand,
                                           const unsigned* __restrict__ gcnt,
                                           const unsigned* __restrict__ flags,
                                           const int* __restrict__ c1v,
                                           unsigned* __restrict__ mid) {
  const int b = blockIdx.z;
  const int c1 = c1v[b];
  __shared__ unsigned lm[1024];
  for (int i = threadIdx.x; i < 1024; i += 256) lm[i] = 0u;
  __syncthreads();
  if (c1 >= 0) {
    const unsigned c1u = (unsigned)c1;
    if (flags[b] == 0u) {
      const uint2* candb = cand + ((size_t)b * CAND_CAP);
      const unsigned n = gcnt[b * 32];
      for (unsigned i = blockIdx.x * 256 + threadIdx.x; i < n; i += gridDim.x * 256) {
        unsigned u = candb[i].x;
        if ((u >> 20) == c1u) atomicAdd(&lm[(u >> 10) & 0x3FFu], 1u);
      }
    } else {
      const float be = beta[b];
      const float4* p4 = (const float4*)(pre + ((size_t)b << 23));
      const float4* g4 = (const float4*)(gum + ((size_t)b << 23));
      for (int i = blockIdx.x * 256 + threadIdx.x; i < (1 << 21); i += gridDim.x * 256) {
        float4 p = p4[i];
        float4 g = g4[i];
        float av[4];
        av[0] = fmaxf(__fadd_rn(p.x, __fmul_rn(be, g.x)), 0.f);
        av[1] = fmaxf(__fadd_rn(p.y, __fmul_rn(be, g.y)), 0.f);
        av[2] = fmaxf(__fadd_rn(p.z, __fmul_rn(be, g.z)), 0.f);
        av[3] = fmaxf(__fadd_rn(p.w, __fmul_rn(be, g.w)), 0.f);
        #pragma unroll
        for (int j = 0; j < 4; j++) {
          unsigned u = __float_as_uint(av[j]);
          if (av[j] > 0.f && (u >> 20) == c1u) atomicAdd(&lm[(u >> 10) & 0x3FFu], 1u);
        }
      }
    }
  }
  __syncthreads();
  for (int i = threadIdx.x; i < 1024; i += 256) {
    unsigned v = lm[i];
    if (v) atomicAdd(&mid[(b << 10) + i], v);
  }
}

// ---------------- K6a: pick c2 ----------------
__global__ __launch_bounds__(256) void k6a(const unsigned* __restrict__ mid,
                                           const int* __restrict__ c1v,
                                           const int* __restrict__ remv,
                                           int* __restrict__ c2v,
                                           int* __restrict__ rem2v) {
  int b = blockIdx.x, t = threadIdx.x;
  if (c1v[b] < 0) return;
  __shared__ unsigned h[1024];
  __shared__ unsigned csum[256];
  for (int i = t; i < 1024; i += 256) h[i] = mid[(b << 10) + i];
  __syncthreads();
  unsigned cs = 0;
  for (int j = 0; j < 4; j++) cs += h[t * 4 + j];
  csum[t] = cs; __syncthreads();
  unsigned suf = 0;
  for (int tt = t + 1; tt < 256; tt++) suf += csum[tt];
  unsigned R = (unsigned)remv[b];
  if (suf < R && suf + cs >= R) {
    unsigned cum = suf;
    for (int j = 3; j >= 0; j--) {
      unsigned hv = h[t * 4 + j];
      cum += hv;
      if (cum >= R) { c2v[b] = t * 4 + j; rem2v[b] = (int)(R - (cum - hv)); break; }
    }
  }
}

// ---------------- K5l: low histogram within (c1,c2) ----------------
__global__ __launch_bounds__(256) void k5l(const float* __restrict__ pre,
                                           const float* __restrict__ gum,
                                           const float* __restrict__ beta,
                                           const uint2* __restrict__ cand,
                                           const unsigned* __restrict__ gcnt,
                                           const unsigned* __restrict__ flags,
                                           const int* __restrict__ c1v,
                                           const int* __restrict__ c2v,
                                           unsigned* __restrict__ low) {
  const int b = blockIdx.z;
  const int c1 = c1v[b];
  __shared__ unsigned lm[1024];
  for (int i = threadIdx.x; i < 1024; i += 256) lm[i] = 0u;
  __syncthreads();
  if (c1 >= 0) {
    const unsigned key = ((unsigned)c1 << 10) | (unsigned)c2v[b];
    if (flags[b] == 0u) {
      const uint2* candb = cand + ((size_t)b * CAND_CAP);
      const unsigned n = gcnt[b * 32];
      for (unsigned i = blockIdx.x * 256 + threadIdx.x; i < n; i += gridDim.x * 256) {
        unsigned u = candb[i].x;
        if ((u >> 10) == key) atomicAdd(&lm[u & 0x3FFu], 1u);
      }
    } else {
      const float be = beta[b];
      const float4* p4 = (const float4*)(pre + ((size_t)b << 23));
      const float4* g4 = (const float4*)(gum + ((size_t)b << 23));
      for (int i = blockIdx.x * 256 + threadIdx.x; i < (1 << 21); i += gridDim.x * 256) {
        float4 p = p4[i];
        float4 g = g4[i];
        float av[4];
        av[0] = fmaxf(__fadd_rn(p.x, __fmul_rn(be, g.x)), 0.f);
        av[1] = fmaxf(__fadd_rn(p.y, __fmul_rn(be, g.y)), 0.f);
        av[2] = fmaxf(__fadd_rn(p.z, __fmul_rn(be, g.z)), 0.f);
        av[3] = fmaxf(__fadd_rn(p.w, __fmul_rn(be, g.w)), 0.f);
        #pragma unroll
        for (int j = 0; j < 4; j++) {
          unsigned u = __float_as_uint(av[j]);
          if (av[j] > 0.f && (u >> 10) == key) atomicAdd(&lm[u & 0x3FFu], 1u);
        }
      }
    }
  }
  __syncthreads();
  for (int i = threadIdx.x; i < 1024; i += 256) {
    unsigned v = lm[i];
    if (v) atomicAdd(&low[(b << 10) + i], v);
  }
}

// ---------------- K6b: exact kth ----------------
__global__ __launch_bounds__(256) void k6b(const unsigned* __restrict__ low,
                                           const int* __restrict__ c1v,
                                           const int* __restrict__ c2v,
                                           const int* __restrict__ rem2v,
                                           float* __restrict__ kth) {
  int b = blockIdx.x, t = threadIdx.x;
  int c1 = c1v[b];
  if (c1 < 0) return;
  __shared__ unsigned h[1024];
  __shared__ unsigned csum[256];
  for (int i = t; i < 1024; i += 256) h[i] = low[(b << 10) + i];
  __syncthreads();
  unsigned cs = 0;
  for (int j = 0; j < 4; j++) cs += h[t * 4 + j];
  csum[t] = cs; __syncthreads();
  unsigned suf = 0;
  for (int tt = t + 1; tt < 256; tt++) suf += csum[tt];
  unsigned R2 = (unsigned)rem2v[b];
  if (suf < R2 && suf + cs >= R2) {
    unsigned cum = suf;
    for (int j = 3; j >= 0; j--) {
      unsigned hv = h[t * 4 + j];
      cum += hv;
      if (cum >= R2) {
        unsigned bits = ((unsigned)c1 << 20) | ((unsigned)c2v[b] << 10) | (unsigned)(t * 4 + j);
        kth[b] = __uint_as_float(bits);
        break;
      }
    }
  }
}

// ---------------- KBUCK: bucket masked candidates by p (into dead pre region) ----------------
__global__ __launch_bounds__(256) void kbuck(const uint2* __restrict__ cand,
                                             const unsigned* __restrict__ gcnt,
                                             const unsigned* __restrict__ flags,
                                             const float* __restrict__ kthv,
                                             unsigned* __restrict__ bcnt,
                                             uint2* __restrict__ buckets) {
  const int b = blockIdx.z;
  if (flags[b]) return;
  const float kv = kthv[b];
  const uint2* cb = cand + ((size_t)b * CAND_CAP);
  const unsigned n = gcnt[b * 32];
  uint2* bb = buckets + ((size_t)b << 22);   // sample stride = 8.4M floats = 4.2M uint2
  unsigned* bc = bcnt + (b << 12);
  for (unsigned i = blockIdx.x * 256 + threadIdx.x; i < n; i += gridDim.x * 256) {
    uint2 e = cb[i];
    if (__uint_as_float(e.x) >= kv) {
      unsigned p = e.y & 4095u;
      unsigned slot = atomicAdd(&bc[p], 1u);
      if (slot < BUCK_CAP) bb[(size_t)p * BUCK_CAP + slot] = e;
    }
  }
}

// ---------------- KRECON: sparse recon from buckets (sorted -> deterministic) ----------------
__global__ __launch_bounds__(256) void krecon(const uint2* __restrict__ buckets,
                                              const unsigned* __restrict__ bcnt,
                                              const unsigned* __restrict__ flags,
                                              const unsigned short* __restrict__ wdb,
                                              const float* __restrict__ b_dec,
                                              float* __restrict__ recon) {
  const int b = blockIdx.z;
  if (flags[b]) return;
  __shared__ uint2 eb[4][BUCK_CAP];
  __shared__ unsigned ncnt[4];
  __shared__ float ot[4][64];
  const int t = threadIdx.x;
  const int p0 = blockIdx.x << 2;
  const unsigned* bc = bcnt + (b << 12);
  if (t < 4) ncnt[t] = min(bc[p0 + t], (unsigned)BUCK_CAP);
  __syncthreads();
  const uint2* bb = buckets + ((size_t)b << 22);
  for (int w = 0; w < 4; ++w) {
    unsigned n = ncnt[w];
    for (unsigned i = t; i < n; i += 256) eb[w][i] = bb[(size_t)(p0 + w) * BUCK_CAP + i];
  }
  __syncthreads();
  if (t < 4) {   // insertion sort by idx (ascending o) for deterministic fp32 order
    unsigned n = ncnt[t];
    for (unsigned i = 1; i < n; ++i) {
      uint2 key = eb[t][i];
      int j = (int)i - 1;
      while (j >= 0 && eb[t][j].y > key.y) { eb[t][j + 1] = eb[t][j]; --j; }
      eb[t][j + 1] = key;
    }
  }
  __syncthreads();
  {
    const int w = t >> 6, c = t & 63;
    unsigned n = ncnt[w];
    float acc = 0.f;
    for (unsigned k = 0; k < n; ++k) {
      uint2 e = eb[w][k];
      unsigned o = e.y >> 12;
      float wv = __uint_as_float(((unsigned)wdb[(o << 6) + c]) << 16);
      acc = fmaf(__uint_as_float(e.x), wv, acc);
    }
    ot[w][c] = acc;
  }
  __syncthreads();
  {
    const int c = t >> 2, pp = t & 3;
    recon[(((size_t)(b * NC + c)) << 12) + p0 + pp] = ot[pp][c] + b_dec[c];
  }
}

// ---------------- KZFILL: zero sparse output (flags==0 samples) ----------------
__global__ __launch_bounds__(256) void kzfill(const unsigned* __restrict__ flags,
                                              float4* __restrict__ sp4) {
  const unsigned total = 1u << 24;   // 16,777,216 float4s = 256MB
  for (unsigned i = blockIdx.x * 256 + threadIdx.x; i < total; i += gridDim.x * 256) {
    int b = i >> 21;
    if (flags[b] == 0u) sp4[i] = make_float4(0.f, 0.f, 0.f, 0.f);
  }
}

// ---------------- KSCAT: scatter masked candidates into sparse ----------------
__global__ __launch_bounds__(256) void kscat(const uint2* __restrict__ cand,
                                             const unsigned* __restrict__ gcnt,
                                             const unsigned* __restrict__ flags,
                                             const float* __restrict__ kthv,
                                             float* __restrict__ sparse) {
  const int b = blockIdx.z;
  if (flags[b]) return;
  const float kv = kthv[b];
  const uint2* cb = cand + ((size_t)b * CAND_CAP);
  const unsigned n = gcnt[b * 32];
  float* sb = sparse + ((size_t)b << 23);
  for (unsigned i = blockIdx.x * 256 + threadIdx.x; i < n; i += gridDim.x * 256) {
    uint2 e = cb[i];
    float v = __uint_as_float(e.x);
    if (v >= kv) sb[e.y] = v;
  }
}

// ---------------- KFB: dense fallback (flagged samples; recompute acts; full pipeline) ----------------
__global__ __launch_bounds__(256, 4) void kfb(float* __restrict__ prespace,
                                              const float* __restrict__ gum,
                                              const float* __restrict__ beta,
                                              const float* __restrict__ kthv,
                                              const unsigned* __restrict__ flags,
                                              const unsigned short* __restrict__ wdb,
                                              const float* __restrict__ b_dec,
                                              float* __restrict__ recon) {
  const int b = blockIdx.z;
  if (!flags[b]) return;
  __shared__ unsigned xsl[64 * 128];
  __shared__ unsigned wtl[64 * 32];
  const int t = threadIdx.x;
  const int pt = blockIdx.x;
  const int p0 = pt << 8;
  const float be = beta[b];
  const float kv = kthv[b];
  const int cg = t >> 5;
  const int pg = t & 31;

  float acc[8][8];
  #pragma unroll
  for (int i = 0; i < 8; i++)
    #pragma unroll
    for (int j = 0; j < 8; j++) acc[i][j] = 0.f;

  for (int tile = 0; tile < 32; ++tile) {
    __syncthreads();
    #pragma unroll
    for (int k = 0; k < 8; ++k) {
      const int ol = 8 * k + (t >> 5);
      const size_t off = (((size_t)(b * HCH + tile * 64 + ol)) << 12) + p0 + ((t & 31) << 3);
      float* pp = prespace + off;
      const float* gp = gum + off;
      float4 pa0 = ((const float4*)pp)[0];
      float4 pa1 = ((const float4*)pp)[1];
      float4 ga0 = ((const float4*)gp)[0];
      float4 ga1 = ((const float4*)gp)[1];
      float4 s0, s1;
      float a;
      a = fmaxf(__fadd_rn(pa0.x, __fmul_rn(be, ga0.x)), 0.f); s0.x = (a >= kv) ? a : 0.f;
      a = fmaxf(__fadd_rn(pa0.y, __fmul_rn(be, ga0.y)), 0.f); s0.y = (a >= kv) ? a : 0.f;
      a = fmaxf(__fadd_rn(pa0.z, __fmul_rn(be, ga0.z)), 0.f); s0.z = (a >= kv) ? a : 0.f;
      a = fmaxf(__fadd_rn(pa0.w, __fmul_rn(be, ga0.w)), 0.f); s0.w = (a >= kv) ? a : 0.f;
      a = fmaxf(__fadd_rn(pa1.x, __fmul_rn(be, ga1.x)), 0.f); s1.x = (a >= kv) ? a : 0.f;
      a = fmaxf(__fadd_rn(pa1.y, __fmul_rn(be, ga1.y)), 0.f); s1.y = (a >= kv) ? a : 0.f;
      a = fmaxf(__fadd_rn(pa1.z, __fmul_rn(be, ga1.z)), 0.f); s1.z = (a >= kv) ? a : 0.f;
      a = fmaxf(__fadd_rn(pa1.w, __fmul_rn(be, ga1.w)), 0.f); s1.w = (a >= kv) ? a : 0.f;
      ((float4*)pp)[0] = s0;   // sparse output in place
      ((float4*)pp)[1] = s1;
      uint4 pk;
      pk.x = bf16r(s0.x) | (bf16r(s0.y) << 16);
      pk.y = bf16r(s0.z) | (bf16r(s0.w) << 16);
      pk.z = bf16r(s1.x) | (bf16r(s1.y) << 16);
      pk.w = bf16r(s1.z) | (bf16r(s1.w) << 16);
      *(uint4*)&xsl[1024 * k + 4 * t] = pk;
    }
    #pragma unroll
    for (int k = 0; k < 2; ++k) {
      const int ol = 32 * k + (t >> 3);
      const uint4 w = *(const uint4*)(wdb + (((size_t)(tile * 64 + ol)) << 6) + ((t & 7) << 3));
      *(uint4*)&wtl[1024 * k + 4 * t] = w;
    }
    __syncthreads();
    #pragma unroll 8
    for (int cc = 0; cc < 64; ++cc) {
      uint4 xv = *(const uint4*)&xsl[cc * 128 + pg * 4];
      uint4 wv = *(const uint4*)&wtl[cc * 32 + cg * 4];
      float xp[8], wf[8];
      xp[0] = __uint_as_float(xv.x << 16); xp[1] = __uint_as_float(xv.x & 0xffff0000u);
      xp[2] = __uint_as_float(xv.y << 16); xp[3] = __uint_as_float(xv.y & 0xffff0000u);
      xp[4] = __uint_as_float(xv.z << 16); xp[5] = __uint_as_float(xv.z & 0xffff0000u);
      xp[6] = __uint_as_float(xv.w << 16); xp[7] = __uint_as_float(xv.w & 0xffff0000u);
      wf[0] = __uint_as_float(wv.x << 16); wf[1] = __uint_as_float(wv.x & 0xffff0000u);
      wf[2] = __uint_as_float(wv.y << 16); wf[3] = __uint_as_float(wv.y & 0xffff0000u);
      wf[4] = __uint_as_float(wv.z << 16); wf[5] = __uint_as_float(wv.z & 0xffff0000u);
      wf[6] = __uint_as_float(wv.w << 16); wf[7] = __uint_as_float(wv.w & 0xffff0000u);
      #pragma unroll
      for (int i = 0; i < 8; i++)
        #pragma unroll
        for (int j = 0; j < 8; j++)
          acc[i][j] = fmaf(wf[i], xp[j], acc[i][j]);
    }
  }

  #pragma unroll
  for (int i = 0; i < 8; ++i) {
    const int c = cg * 8 + i;
    const float bd = b_dec[c];
    float* pr = recon + (((size_t)(b * NC + c)) << 12) + p0 + pg * 8;
    *(float4*)pr       = make_float4(acc[i][0] + bd, acc[i][1] + bd, acc[i][2] + bd, acc[i][3] + bd);
    *(float4*)(pr + 4) = make_float4(acc[i][4] + bd, acc[i][5] + bd, acc[i][6] + bd, acc[i][7] + bd);
  }
}

extern "C" void kernel_launch(void* const* d_in, const int* in_sizes, int n_in,
                              void* d_out, int out_size, void* d_ws, size_t ws_size,
                              hipStream_t stream) {
  const float* x     = (const float*)d_in[0];
  const float* W     = (const float*)d_in[1];
  const float* b_enc = (const float*)d_in[2];
  const float* b_dec = (const float*)d_in[3];
  const float* gum   = (const float*)d_in[4];
  float* recon  = (float*)d_out;
  float* sparse = recon + RECON_N;   // pre scratch -> buckets -> sparse output

  char* ws = (char*)d_ws;
  uint2*    cand  = (uint2*)(ws + WS_CAND);
  unsigned short* wdb = (unsigned short*)(ws + WS_WD);
  unsigned* ghist = (unsigned*)(ws + WS_GHIST);
  unsigned* mid   = (unsigned*)(ws + WS_MID);
  unsigned* low   = (unsigned*)(ws + WS_LOW);
  double*   part  = (double*)(ws + WS_PART);
  float*    normv = (float*)(ws + WS_NORM);
  float*    beta  = (float*)(ws + WS_BETA);
  unsigned* binT0 = (unsigned*)(ws + WS_BINT0);
  int*      c1v   = (int*)(ws + WS_C1);
  int*      remv  = (int*)(ws + WS_REM);
  int*      c2v   = (int*)(ws + WS_C2);
  int*      rem2v = (int*)(ws + WS_REM2);
  float*    kth   = (float*)(ws + WS_KTH);
  unsigned* flags = (unsigned*)(ws + WS_FLAGS);
  unsigned* gcnt  = (unsigned*)(ws + WS_GCNT);
  unsigned* bcnt  = (unsigned*)(ws + WS_BCNT);

  hipMemsetAsync(ws + WS_GHIST, 0, 131072, stream);                 // ghist+mid+low
  hipMemsetAsync(ws + WS_FLAGS, 0, WS_BCNT + 131072 - WS_FLAGS, stream);  // flags+gcnt+bcnt

  k0a_norm <<<64, 256, 0, stream>>>(W, normv);
  k0b_wd   <<<512, 256, 0, stream>>>(W, normv, wdb);
  k1_encode<<<dim3(32, 16, NB), 256, 0, stream>>>(x, W, b_enc, b_dec, sparse, part);
  k2_beta  <<<NB, 256, 0, stream>>>(part, beta, binT0);
  k3_acts  <<<dim3(1024, 1, NB), 256, 0, stream>>>(sparse, gum, beta, binT0, ghist, cand, gcnt, flags);
  k4a_check<<<NB, 256, 0, stream>>>(ghist, flags);
  k3fb     <<<dim3(1024, 1, NB), 256, 0, stream>>>(sparse, gum, beta, binT0, flags, ghist);
  k4_coarse<<<NB, 256, 0, stream>>>(ghist, c1v, remv, kth);
  k5m      <<<dim3(256, 1, NB), 256, 0, stream>>>(sparse, gum, beta, cand, gcnt, flags, c1v, mid);
  k6a      <<<NB, 256, 0, stream>>>(mid, c1v, remv, c2v, rem2v);
  k5l      <<<dim3(256, 1, NB), 256, 0, stream>>>(sparse, gum, beta, cand, gcnt, flags, c1v, c2v, low);
  k6b      <<<NB, 256, 0, stream>>>(low, c1v, c2v, rem2v, kth);
  kbuck    <<<dim3(256, 1, NB), 256, 0, stream>>>(cand, gcnt, flags, kth, bcnt, (uint2*)sparse);
  krecon   <<<dim3(1024, 1, NB), 256, 0, stream>>>((const uint2*)sparse, bcnt, flags, wdb, b_dec, recon);
  kzfill   <<<8192, 256, 0, stream>>>(flags, (float4*)sparse);
  kscat    <<<dim3(256, 1, NB), 256, 0, stream>>>(cand, gcnt, flags, kth, sparse);
  kfb      <<<dim3(16, 1, NB), 256, 0, stream>>>(sparse, gum, beta, kth, flags, wdb, b_dec, recon);
}

// Round 14
// 593.470 us; speedup vs baseline: 1.5766x; 1.5766x over previous
//
#include <hip/hip_runtime.h>
#include <hip/hip_bf16.h>
#include <math.h>

// Problem constants
#define NB    8
#define NC    64
#define HWP   4096          // H*W
#define HCH   2048
#define NSAMP 8388608       // HC*H*W per sample
#define KSEL  167772u       // int(0.02 * NSAMP)
#define RECON_N 2097152     // B*C*H*W
#define CAND_CAP 524288u    // per-sample candidate entries (uint2 = 8B) -> 4MB/sample
#define CBUF_CAP 1536u      // per-block LDS candidate buffer (exp ~400/block)
#define BUCK_CAP 256u       // per-(b,p) bucket capacity (mean 41; overflow -> exact kfb path)

// Workspace layout (bytes)
#define WS_CAND   0u          // 8 * 524288 * 8 = 33554432
#define WS_WD     33554432u   // wd bf16: 131072 * 2
#define WS_GHIST  33816576u   // 8*2048*4 = 65536
#define WS_MID    33882112u   // 8*1024*4 = 32768
#define WS_LOW    33914880u   // 8*1024*4 = 32768
#define WS_PART   33947648u   // 8*512*2*8 doubles = 65536 (region holds 262144)
#define WS_NORM   34209792u
#define WS_BETA   34210048u
#define WS_BINT0  34210080u
#define WS_C1     34210112u
#define WS_REM    34210144u
#define WS_C2     34210176u
#define WS_REM2   34210208u
#define WS_KTH    34210240u
#define WS_FLAGS  34210304u   // 8*4 (bit0: hist insufficiency, bit1: cand ovf, bit2: bucket ovf)
#define WS_GCNT   34210432u   // 8 counters padded 128B = 1024
#define WS_BCNT   34211456u   // 8*4096*4 = 131072 (pass-1 counts)
#define WS_BCNT2  34342528u   // 8*4096*4 = 131072 (pass-2 slots) -> ends 34473600

__device__ __forceinline__ unsigned bf16r(float f) {   // RNE round to bf16
  unsigned u = __float_as_uint(f);
  unsigned r = (u >> 16) & 1u;
  return (u + 0x7fffu + r) >> 16;
}

// ---------------- K0a: decoder column norms ----------------
__global__ __launch_bounds__(256) void k0a_norm(const float* __restrict__ W,
                                                float* __restrict__ normv) {
  __shared__ float red[256];
  int c = blockIdx.x, t = threadIdx.x;
  float s = 0.f;
  for (int o = t; o < HCH; o += 256) { float w = W[o * NC + c]; s += w * w; }
  red[t] = s; __syncthreads();
  for (int off = 128; off; off >>= 1) { if (t < off) red[t] += red[t + off]; __syncthreads(); }
  if (t == 0) normv[c] = fmaxf(sqrtf(red[0]), 1e-12f);
}

// ---------------- K0b: wdb[o][c] = bf16(W[o][c] / norm[c]) ----------------
__global__ __launch_bounds__(256) void k0b_wd(const float* __restrict__ W,
                                              const float* __restrict__ normv,
                                              unsigned short* __restrict__ wdb) {
  int i = blockIdx.x * 256 + threadIdx.x;
  if (i < HCH * NC) wdb[i] = (unsigned short)bf16r(W[i] / normv[i & 63]);
}

// ---------------- K1: encode GEMM (128x128 tile, 8x8 micro) + sum/sumsq ----------------
__global__ __launch_bounds__(256) void k1_encode(const float* __restrict__ x,
                                                 const float* __restrict__ W,
                                                 const float* __restrict__ b_enc,
                                                 const float* __restrict__ b_dec,
                                                 float* __restrict__ pre,
                                                 double* __restrict__ part) {
  __shared__ float xs[64][128];   // [c][p]
  __shared__ float wt[64][128];   // [c][o]
  const int t = threadIdx.x;
  const int pt = blockIdx.x;      // 0..31
  const int ot = blockIdx.y;      // 0..15
  const int b  = blockIdx.z;
  const int p0 = pt << 7, o0 = ot << 7;

  {
    const int c  = t >> 2;
    const int pc = (t & 3) << 5;
    const float* xp = x + (((size_t)(b * NC + c)) << 12) + p0 + pc;
    const float bd = b_dec[c];
    #pragma unroll
    for (int j = 0; j < 8; j++) {
      float4 v = ((const float4*)xp)[j];
      v.x -= bd; v.y -= bd; v.z -= bd; v.w -= bd;
      *(float4*)&xs[c][pc + 4 * j] = v;
    }
    const int ol = t >> 1;
    const int c0 = (t & 1) << 5;
    const float* wp = W + (((size_t)(o0 + ol)) << 6) + c0;
    #pragma unroll
    for (int j = 0; j < 8; j++) {
      float4 w4 = ((const float4*)wp)[j];
      wt[c0 + 4 * j + 0][ol] = w4.x;
      wt[c0 + 4 * j + 1][ol] = w4.y;
      wt[c0 + 4 * j + 2][ol] = w4.z;
      wt[c0 + 4 * j + 3][ol] = w4.w;
    }
  }
  __syncthreads();

  const int og = (t >> 4) << 3;
  const int pg = (t & 15) << 3;
  float acc[8][8];
  #pragma unroll
  for (int i = 0; i < 8; i++)
    #pragma unroll
    for (int j = 0; j < 8; j++) acc[i][j] = 0.f;

  #pragma unroll 8
  for (int cc = 0; cc < 64; cc++) {
    float4 w0 = *(const float4*)&wt[cc][og];
    float4 w1 = *(const float4*)&wt[cc][og + 4];
    float4 x0 = *(const float4*)&xs[cc][pg];
    float4 x1 = *(const float4*)&xs[cc][pg + 4];
    float wv[8] = {w0.x, w0.y, w0.z, w0.w, w1.x, w1.y, w1.z, w1.w};
    float xv[8] = {x0.x, x0.y, x0.z, x0.w, x1.x, x1.y, x1.z, x1.w};
    #pragma unroll
    for (int i = 0; i < 8; i++)
      #pragma unroll
      for (int j = 0; j < 8; j++)
        acc[i][j] += wv[i] * xv[j];
  }

  double s = 0.0, s2 = 0.0;
  #pragma unroll
  for (int i = 0; i < 8; i++) {
    const float be = b_enc[o0 + og + i];
    float r[8];
    #pragma unroll
    for (int j = 0; j < 8; j++) {
      r[j] = acc[i][j] + be;
      double d = (double)r[j];
      s += d; s2 += d * d;
    }
    float* pp = pre + (((size_t)(b * HCH + o0 + og + i)) << 12) + p0 + pg;
    *(float4*)pp       = make_float4(r[0], r[1], r[2], r[3]);
    *(float4*)(pp + 4) = make_float4(r[4], r[5], r[6], r[7]);
  }
  #pragma unroll
  for (int off = 32; off; off >>= 1) { s += __shfl_down(s, off); s2 += __shfl_down(s2, off); }
  __syncthreads();
  double* redd = (double*)&xs[0][0];
  if ((t & 63) == 0) { redd[(t >> 6) * 2] = s; redd[(t >> 6) * 2 + 1] = s2; }
  __syncthreads();
  if (t == 0) {
    double ts = redd[0] + redd[2] + redd[4] + redd[6];
    double t2 = redd[1] + redd[3] + redd[5] + redd[7];
    int pidx = (b * 16 + ot) * 32 + pt;
    part[2 * pidx] = ts; part[2 * pidx + 1] = t2;
  }
}

// ---------------- K2: reduce -> beta, binT0 (3.0*beta) ----------------
__global__ __launch_bounds__(256) void k2_beta(const double* __restrict__ part,
                                               float* __restrict__ beta,
                                               unsigned* __restrict__ binT0) {
  __shared__ double sd[256], sd2[256];
  int b = blockIdx.x, t = threadIdx.x;
  double s = 0.0, s2 = 0.0;
  for (int j = 0; j < 2; j++) {
    int pi = b * 512 + t * 2 + j;
    s += part[2 * pi]; s2 += part[2 * pi + 1];
  }
  sd[t] = s; sd2[t] = s2; __syncthreads();
  for (int off = 128; off; off >>= 1) {
    if (t < off) { sd[t] += sd[t + off]; sd2[t] += sd2[t + off]; }
    __syncthreads();
  }
  if (t == 0) {
    const double n = (double)NSAMP;
    double var = (sd2[0] - sd[0] * sd[0] / n) / (n - 1.0);
    if (var < 0.0) var = 0.0;
    float bv = (float)(sqrt(var) * 10.000001);
    beta[b] = bv;
    binT0[b] = __float_as_uint(3.0f * bv) >> 20;
  }
}

// ---------------- K3: hist + (val,idx) candidate compaction; NO acts write ----------------
__global__ __launch_bounds__(256) void k3_acts(const float* __restrict__ pre,
                                               const float* __restrict__ gum,
                                               const float* __restrict__ beta,
                                               const unsigned* __restrict__ binT0,
                                               unsigned* __restrict__ ghist,
                                               uint2* __restrict__ cand,
                                               unsigned* __restrict__ gcnt,
                                               unsigned* __restrict__ flags) {
  __shared__ unsigned lh[2048];
  __shared__ uint2 cbuf[CBUF_CAP];
  __shared__ unsigned lcnt, gbase;
  const int b = blockIdx.z;
  const float be = beta[b];
  const unsigned bT0 = binT0[b];
  const int lane = threadIdx.x & 63;
  const unsigned long long lm_lt = (1ull << lane) - 1ull;
  for (int i = threadIdx.x; i < 2048; i += 256) lh[i] = 0u;
  if (threadIdx.x == 0) lcnt = 0u;
  __syncthreads();
  const float4* p4 = (const float4*)(pre + ((size_t)b << 23));
  const float4* g4 = (const float4*)(gum + ((size_t)b << 23));
  const int per4 = 1 << 21;
  for (int i = blockIdx.x * 256 + threadIdx.x; i < per4; i += gridDim.x * 256) {
    float4 p = p4[i];
    float4 g = g4[i];
    float4 a;
    a.x = fmaxf(__fadd_rn(p.x, __fmul_rn(be, g.x)), 0.f);
    a.y = fmaxf(__fadd_rn(p.y, __fmul_rn(be, g.y)), 0.f);
    a.z = fmaxf(__fadd_rn(p.z, __fmul_rn(be, g.z)), 0.f);
    a.w = fmaxf(__fadd_rn(p.w, __fmul_rn(be, g.w)), 0.f);
    unsigned u0 = __float_as_uint(a.x), u1 = __float_as_uint(a.y);
    unsigned u2 = __float_as_uint(a.z), u3 = __float_as_uint(a.w);
    bool c0 = (a.x > 0.f) && ((u0 >> 20) >= bT0);
    bool c1 = (a.y > 0.f) && ((u1 >> 20) >= bT0);
    bool c2 = (a.z > 0.f) && ((u2 >> 20) >= bT0);
    bool c3 = (a.w > 0.f) && ((u3 >> 20) >= bT0);
    unsigned long long m0 = __ballot(c0), m1 = __ballot(c1);
    unsigned long long m2 = __ballot(c2), m3 = __ballot(c3);
    unsigned n0 = __popcll(m0), n1 = __popcll(m1), n2 = __popcll(m2), n3 = __popcll(m3);
    unsigned tot = n0 + n1 + n2 + n3;
    if (tot) {
      unsigned base = 0;
      if (lane == 0) base = atomicAdd(&lcnt, tot);
      base = (unsigned)__shfl((int)base, 0);
      unsigned i0 = base + __popcll(m0 & lm_lt);
      unsigned i1 = base + n0 + __popcll(m1 & lm_lt);
      unsigned i2 = base + n0 + n1 + __popcll(m2 & lm_lt);
      unsigned i3 = base + n0 + n1 + n2 + __popcll(m3 & lm_lt);
      const unsigned ib = ((unsigned)i) << 2;
      if (c0 && i0 < CBUF_CAP) cbuf[i0] = make_uint2(u0, ib | 0u);
      if (c1 && i1 < CBUF_CAP) cbuf[i1] = make_uint2(u1, ib | 1u);
      if (c2 && i2 < CBUF_CAP) cbuf[i2] = make_uint2(u2, ib | 2u);
      if (c3 && i3 < CBUF_CAP) cbuf[i3] = make_uint2(u3, ib | 3u);
      if (c0) atomicAdd(&lh[u0 >> 20], 1u);
      if (c1) atomicAdd(&lh[u1 >> 20], 1u);
      if (c2) atomicAdd(&lh[u2 >> 20], 1u);
      if (c3) atomicAdd(&lh[u3 >> 20], 1u);
    }
  }
  __syncthreads();
  if (threadIdx.x == 0) {
    unsigned n = lcnt;
    if (n > CBUF_CAP) { atomicOr(&flags[b], 2u); n = CBUF_CAP; }
    unsigned gb = atomicAdd(&gcnt[b * 32], n);
    if (gb + n > CAND_CAP) atomicOr(&flags[b], 2u);
    gbase = gb;
  }
  __syncthreads();
  {
    uint2* candb = cand + ((size_t)b * CAND_CAP);
    const unsigned n = (lcnt > CBUF_CAP) ? CBUF_CAP : lcnt;
    const unsigned gb = gbase;
    for (unsigned i = threadIdx.x; i < n; i += 256) {
      unsigned d = gb + i;
      if (d < CAND_CAP) candb[d] = cbuf[i];
    }
  }
  for (int i = threadIdx.x; i < 2048; i += 256) {
    unsigned v = lh[i];
    if (v) atomicAdd(&ghist[(b << 11) + i], v);
  }
}

// ---------------- K4a: restricted-hist sufficiency ----------------
__global__ __launch_bounds__(256) void k4a_check(const unsigned* __restrict__ ghist,
                                                 unsigned* __restrict__ flags) {
  __shared__ unsigned red[256];
  int b = blockIdx.x, t = threadIdx.x;
  unsigned s = 0;
  for (int j = 0; j < 8; j++) s += ghist[(b << 11) + t * 8 + j];
  red[t] = s; __syncthreads();
  for (int off = 128; off; off >>= 1) { if (t < off) red[t] += red[t + off]; __syncthreads(); }
  if (t == 0 && red[0] < KSEL) atomicOr(&flags[b], 1u);
}

// ---------------- K3fb: fallback low-bin histogram (recompute acts) ----------------
__global__ __launch_bounds__(256) void k3fb(const float* __restrict__ pre,
                                            const float* __restrict__ gum,
                                            const float* __restrict__ beta,
                                            const unsigned* __restrict__ binT0,
                                            const unsigned* __restrict__ flags,
                                            unsigned* __restrict__ ghist) {
  const int b = blockIdx.z;
  if ((flags[b] & 1u) == 0u) return;
  __shared__ unsigned lh[8192];
  const float be = beta[b];
  const unsigned bT0 = binT0[b];
  const unsigned sub = threadIdx.x & 3;
  for (int i = threadIdx.x; i < 8192; i += 256) lh[i] = 0u;
  __syncthreads();
  const float4* p4 = (const float4*)(pre + ((size_t)b << 23));
  const float4* g4 = (const float4*)(gum + ((size_t)b << 23));
  for (int i = blockIdx.x * 256 + threadIdx.x; i < (1 << 21); i += gridDim.x * 256) {
    float4 p = p4[i];
    float4 g = g4[i];
    float av[4];
    av[0] = fmaxf(__fadd_rn(p.x, __fmul_rn(be, g.x)), 0.f);
    av[1] = fmaxf(__fadd_rn(p.y, __fmul_rn(be, g.y)), 0.f);
    av[2] = fmaxf(__fadd_rn(p.z, __fmul_rn(be, g.z)), 0.f);
    av[3] = fmaxf(__fadd_rn(p.w, __fmul_rn(be, g.w)), 0.f);
    #pragma unroll
    for (int j = 0; j < 4; j++) {
      unsigned u = __float_as_uint(av[j]);
      if (av[j] > 0.f && (u >> 20) < bT0) atomicAdd(&lh[((u >> 20) << 2) | sub], 1u);
    }
  }
  __syncthreads();
  for (int i = threadIdx.x; i < 2048; i += 256) {
    unsigned v = lh[4 * i] + lh[4 * i + 1] + lh[4 * i + 2] + lh[4 * i + 3];
    if (v) atomicAdd(&ghist[(b << 11) + i], v);
  }
}

// ---------------- K4: pick coarse bin ----------------
__global__ __launch_bounds__(256) void k4_coarse(const unsigned* __restrict__ ghist,
                                                 int* __restrict__ c1v,
                                                 int* __restrict__ remv,
                                                 float* __restrict__ kth) {
  __shared__ unsigned h[2048];
  __shared__ unsigned csum[256];
  int b = blockIdx.x, t = threadIdx.x;
  for (int i = t; i < 2048; i += 256) h[i] = ghist[(b << 11) + i];
  __syncthreads();
  unsigned cs = 0;
  for (int j = 0; j < 8; j++) cs += h[t * 8 + j];
  csum[t] = cs; __syncthreads();
  unsigned suf = 0;
  for (int tt = t + 1; tt < 256; tt++) suf += csum[tt];
  if (suf < KSEL && suf + cs >= KSEL) {
    unsigned cum = suf;
    for (int j = 7; j >= 0; j--) {
      unsigned hv = h[t * 8 + j];
      cum += hv;
      if (cum >= KSEL) { c1v[b] = t * 8 + j; remv[b] = (int)(KSEL - (cum - hv)); break; }
    }
  }
  if (t == 0) {
    unsigned tot = 0;
    for (int tt = 0; tt < 256; tt++) tot += csum[tt];
    if (tot < KSEL) { c1v[b] = -1; kth[b] = 0.f; }
  }
}

// ---------------- K5m: mid histogram within c1 ----------------
__global__ __launch_bounds__(256) void k5m(const float* __restrict__ pre,
                                           const float* __restrict__ gum,
                                           const float* __restrict__ beta,
                                           const uint2* __restrict__ cand,
                                           const unsigned* __restrict__ gcnt,
                                           const unsigned* __restrict__ flags,
                                           const int* __restrict__ c1v,
                                           unsigned* __restrict__ mid) {
  const int b = blockIdx.z;
  const int c1 = c1v[b];
  __shared__ unsigned lm[1024];
  for (int i = threadIdx.x; i < 1024; i += 256) lm[i] = 0u;
  __syncthreads();
  if (c1 >= 0) {
    const unsigned c1u = (unsigned)c1;
    if (flags[b] == 0u) {
      const uint2* candb = cand + ((size_t)b * CAND_CAP);
      const unsigned n = gcnt[b * 32];
      for (unsigned i = blockIdx.x * 256 + threadIdx.x; i < n; i += gridDim.x * 256) {
        unsigned u = candb[i].x;
        if ((u >> 20) == c1u) atomicAdd(&lm[(u >> 10) & 0x3FFu], 1u);
      }
    } else {
      const float be = beta[b];
      const float4* p4 = (const float4*)(pre + ((size_t)b << 23));
      const float4* g4 = (const float4*)(gum + ((size_t)b << 23));
      for (int i = blockIdx.x * 256 + threadIdx.x; i < (1 << 21); i += gridDim.x * 256) {
        float4 p = p4[i];
        float4 g = g4[i];
        float av[4];
        av[0] = fmaxf(__fadd_rn(p.x, __fmul_rn(be, g.x)), 0.f);
        av[1] = fmaxf(__fadd_rn(p.y, __fmul_rn(be, g.y)), 0.f);
        av[2] = fmaxf(__fadd_rn(p.z, __fmul_rn(be, g.z)), 0.f);
        av[3] = fmaxf(__fadd_rn(p.w, __fmul_rn(be, g.w)), 0.f);
        #pragma unroll
        for (int j = 0; j < 4; j++) {
          unsigned u = __float_as_uint(av[j]);
          if (av[j] > 0.f && (u >> 20) == c1u) atomicAdd(&lm[(u >> 10) & 0x3FFu], 1u);
        }
      }
    }
  }
  __syncthreads();
  for (int i = threadIdx.x; i < 1024; i += 256) {
    unsigned v = lm[i];
    if (v) atomicAdd(&mid[(b << 10) + i], v);
  }
}

// ---------------- K6a: pick c2 ----------------
__global__ __launch_bounds__(256) void k6a(const unsigned* __restrict__ mid,
                                           const int* __restrict__ c1v,
                                           const int* __restrict__ remv,
                                           int* __restrict__ c2v,
                                           int* __restrict__ rem2v) {
  int b = blockIdx.x, t = threadIdx.x;
  if (c1v[b] < 0) return;
  __shared__ unsigned h[1024];
  __shared__ unsigned csum[256];
  for (int i = t; i < 1024; i += 256) h[i] = mid[(b << 10) + i];
  __syncthreads();
  unsigned cs = 0;
  for (int j = 0; j < 4; j++) cs += h[t * 4 + j];
  csum[t] = cs; __syncthreads();
  unsigned suf = 0;
  for (int tt = t + 1; tt < 256; tt++) suf += csum[tt];
  unsigned R = (unsigned)remv[b];
  if (suf < R && suf + cs >= R) {
    unsigned cum = suf;
    for (int j = 3; j >= 0; j--) {
      unsigned hv = h[t * 4 + j];
      cum += hv;
      if (cum >= R) { c2v[b] = t * 4 + j; rem2v[b] = (int)(R - (cum - hv)); break; }
    }
  }
}

// ---------------- K5l: low histogram within (c1,c2) ----------------
__global__ __launch_bounds__(256) void k5l(const float* __restrict__ pre,
                                           const float* __restrict__ gum,
                                           const float* __restrict__ beta,
                                           const uint2* __restrict__ cand,
                                           const unsigned* __restrict__ gcnt,
                                           const unsigned* __restrict__ flags,
                                           const int* __restrict__ c1v,
                                           const int* __restrict__ c2v,
                                           unsigned* __restrict__ low) {
  const int b = blockIdx.z;
  const int c1 = c1v[b];
  __shared__ unsigned lm[1024];
  for (int i = threadIdx.x; i < 1024; i += 256) lm[i] = 0u;
  __syncthreads();
  if (c1 >= 0) {
    const unsigned key = ((unsigned)c1 << 10) | (unsigned)c2v[b];
    if (flags[b] == 0u) {
      const uint2* candb = cand + ((size_t)b * CAND_CAP);
      const unsigned n = gcnt[b * 32];
      for (unsigned i = blockIdx.x * 256 + threadIdx.x; i < n; i += gridDim.x * 256) {
        unsigned u = candb[i].x;
        if ((u >> 10) == key) atomicAdd(&lm[u & 0x3FFu], 1u);
      }
    } else {
      const float be = beta[b];
      const float4* p4 = (const float4*)(pre + ((size_t)b << 23));
      const float4* g4 = (const float4*)(gum + ((size_t)b << 23));
      for (int i = blockIdx.x * 256 + threadIdx.x; i < (1 << 21); i += gridDim.x * 256) {
        float4 p = p4[i];
        float4 g = g4[i];
        float av[4];
        av[0] = fmaxf(__fadd_rn(p.x, __fmul_rn(be, g.x)), 0.f);
        av[1] = fmaxf(__fadd_rn(p.y, __fmul_rn(be, g.y)), 0.f);
        av[2] = fmaxf(__fadd_rn(p.z, __fmul_rn(be, g.z)), 0.f);
        av[3] = fmaxf(__fadd_rn(p.w, __fmul_rn(be, g.w)), 0.f);
        #pragma unroll
        for (int j = 0; j < 4; j++) {
          unsigned u = __float_as_uint(av[j]);
          if (av[j] > 0.f && (u >> 10) == key) atomicAdd(&lm[u & 0x3FFu], 1u);
        }
      }
    }
  }
  __syncthreads();
  for (int i = threadIdx.x; i < 1024; i += 256) {
    unsigned v = lm[i];
    if (v) atomicAdd(&low[(b << 10) + i], v);
  }
}

// ---------------- K6b: exact kth ----------------
__global__ __launch_bounds__(256) void k6b(const unsigned* __restrict__ low,
                                           const int* __restrict__ c1v,
                                           const int* __restrict__ c2v,
                                           const int* __restrict__ rem2v,
                                           float* __restrict__ kth) {
  int b = blockIdx.x, t = threadIdx.x;
  int c1 = c1v[b];
  if (c1 < 0) return;
  __shared__ unsigned h[1024];
  __shared__ unsigned csum[256];
  for (int i = t; i < 1024; i += 256) h[i] = low[(b << 10) + i];
  __syncthreads();
  unsigned cs = 0;
  for (int j = 0; j < 4; j++) cs += h[t * 4 + j];
  csum[t] = cs; __syncthreads();
  unsigned suf = 0;
  for (int tt = t + 1; tt < 256; tt++) suf += csum[tt];
  unsigned R2 = (unsigned)rem2v[b];
  if (suf < R2 && suf + cs >= R2) {
    unsigned cum = suf;
    for (int j = 3; j >= 0; j--) {
      unsigned hv = h[t * 4 + j];
      cum += hv;
      if (cum >= R2) {
        unsigned bits = ((unsigned)c1 << 20) | ((unsigned)c2v[b] << 10) | (unsigned)(t * 4 + j);
        kth[b] = __uint_as_float(bits);
        break;
      }
    }
  }
}

// ---------------- KBUCK1: count masked candidates per p (pre intact) ----------------
__global__ __launch_bounds__(256) void kbuck1(const uint2* __restrict__ cand,
                                              const unsigned* __restrict__ gcnt,
                                              const unsigned* __restrict__ flags,
                                              const float* __restrict__ kthv,
                                              unsigned* __restrict__ bcnt) {
  const int b = blockIdx.z;
  if (flags[b]) return;
  const float kv = kthv[b];
  const uint2* cb = cand + ((size_t)b * CAND_CAP);
  const unsigned n = gcnt[b * 32];
  unsigned* bc = bcnt + (b << 12);
  for (unsigned i = blockIdx.x * 256 + threadIdx.x; i < n; i += gridDim.x * 256) {
    uint2 e = cb[i];
    if (__uint_as_float(e.x) >= kv) atomicAdd(&bc[e.y & 4095u], 1u);
  }
}

// ---------------- KCHK: flag bucket overflow (bit2) BEFORE pre is overwritten ----------------
__global__ __launch_bounds__(256) void kchk(const unsigned* __restrict__ bcnt,
                                            unsigned* __restrict__ flags) {
  __shared__ unsigned red[256];
  int b = blockIdx.x, t = threadIdx.x;
  unsigned m = 0;
  for (int j = 0; j < 16; j++) m = max(m, bcnt[(b << 12) + t * 16 + j]);
  red[t] = m; __syncthreads();
  for (int off = 128; off; off >>= 1) { if (t < off) red[t] = max(red[t], red[t + off]); __syncthreads(); }
  if (t == 0 && red[0] > BUCK_CAP) atomicOr(&flags[b], 4u);
}

// ---------------- KBUCK2: fill buckets (into dead pre region) ----------------
__global__ __launch_bounds__(256) void kbuck2(const uint2* __restrict__ cand,
                                              const unsigned* __restrict__ gcnt,
                                              const unsigned* __restrict__ flags,
                                              const float* __restrict__ kthv,
                                              unsigned* __restrict__ bcnt2,
                                              uint2* __restrict__ buckets) {
  const int b = blockIdx.z;
  if (flags[b]) return;
  const float kv = kthv[b];
  const uint2* cb = cand + ((size_t)b * CAND_CAP);
  const unsigned n = gcnt[b * 32];
  uint2* bb = buckets + ((size_t)b << 22);
  unsigned* bc = bcnt2 + (b << 12);
  for (unsigned i = blockIdx.x * 256 + threadIdx.x; i < n; i += gridDim.x * 256) {
    uint2 e = cb[i];
    if (__uint_as_float(e.x) >= kv) {
      unsigned p = e.y & 4095u;
      unsigned slot = atomicAdd(&bc[p], 1u);
      bb[(size_t)p * BUCK_CAP + slot] = e;   // slot < BUCK_CAP guaranteed by kchk
    }
  }
}

// ---------------- KRECON: sparse recon (parallel rank sort -> deterministic) ----------------
__global__ __launch_bounds__(256) void krecon(const uint2* __restrict__ buckets,
                                              const unsigned* __restrict__ bcnt2,
                                              const unsigned* __restrict__ flags,
                                              const unsigned short* __restrict__ wdb,
                                              const float* __restrict__ b_dec,
                                              float* __restrict__ recon) {
  const int b = blockIdx.z;
  if (flags[b]) return;
  __shared__ uint2 eb[4][BUCK_CAP];
  __shared__ uint2 es[4][BUCK_CAP];
  __shared__ unsigned ncnt[4];
  __shared__ float ot[4][64];
  const int t = threadIdx.x;
  const int p0 = blockIdx.x << 2;
  if (t < 4) ncnt[t] = bcnt2[(b << 12) + p0 + t];
  __syncthreads();
  const uint2* bb = buckets + ((size_t)b << 22);
  for (int w = 0; w < 4; ++w) {
    unsigned n = ncnt[w];
    for (unsigned i = t; i < n; i += 256) eb[w][i] = bb[(size_t)(p0 + w) * BUCK_CAP + i];
  }
  __syncthreads();
  {  // parallel rank sort by idx: 64 lanes per bucket
    const int w = t >> 6, lane = t & 63;
    unsigned n = ncnt[w];
    for (unsigned i = lane; i < n; i += 64) {
      unsigned key = eb[w][i].y;
      unsigned rank = 0;
      for (unsigned j = 0; j < n; ++j) rank += (eb[w][j].y < key) ? 1u : 0u;
      es[w][rank] = eb[w][i];
    }
  }
  __syncthreads();
  {
    const int w = t >> 6, c = t & 63;
    unsigned n = ncnt[w];
    float acc = 0.f;
    unsigned k = 0;
    for (; k + 4 <= n; k += 4) {   // 4x unroll: independent L2-hot wd loads
      uint2 e0 = es[w][k], e1 = es[w][k + 1], e2 = es[w][k + 2], e3 = es[w][k + 3];
      float w0 = __uint_as_float(((unsigned)wdb[((e0.y >> 12) << 6) + c]) << 16);
      float w1 = __uint_as_float(((unsigned)wdb[((e1.y >> 12) << 6) + c]) << 16);
      float w2 = __uint_as_float(((unsigned)wdb[((e2.y >> 12) << 6) + c]) << 16);
      float w3 = __uint_as_float(((unsigned)wdb[((e3.y >> 12) << 6) + c]) << 16);
      acc = fmaf(__uint_as_float(e0.x), w0, acc);
      acc = fmaf(__uint_as_float(e1.x), w1, acc);
      acc = fmaf(__uint_as_float(e2.x), w2, acc);
      acc = fmaf(__uint_as_float(e3.x), w3, acc);
    }
    for (; k < n; ++k) {
      uint2 e = es[w][k];
      float wv = __uint_as_float(((unsigned)wdb[((e.y >> 12) << 6) + c]) << 16);
      acc = fmaf(__uint_as_float(e.x), wv, acc);
    }
    ot[w][c] = acc;
  }
  __syncthreads();
  {
    const int c = t >> 2, pp = t & 3;
    recon[(((size_t)(b * NC + c)) << 12) + p0 + pp] = ot[pp][c] + b_dec[c];
  }
}

// ---------------- KZFILL: zero sparse output (non-flagged samples) ----------------
__global__ __launch_bounds__(256) void kzfill(const unsigned* __restrict__ flags,
                                              float4* __restrict__ sp4) {
  const unsigned total = 1u << 24;
  for (unsigned i = blockIdx.x * 256 + threadIdx.x; i < total; i += gridDim.x * 256) {
    int b = i >> 21;
    if (flags[b] == 0u) sp4[i] = make_float4(0.f, 0.f, 0.f, 0.f);
  }
}

// ---------------- KSCAT: scatter masked candidates into sparse ----------------
__global__ __launch_bounds__(256) void kscat(const uint2* __restrict__ cand,
                                             const unsigned* __restrict__ gcnt,
                                             const unsigned* __restrict__ flags,
                                             const float* __restrict__ kthv,
                                             float* __restrict__ sparse) {
  const int b = blockIdx.z;
  if (flags[b]) return;
  const float kv = kthv[b];
  const uint2* cb = cand + ((size_t)b * CAND_CAP);
  const unsigned n = gcnt[b * 32];
  float* sb = sparse + ((size_t)b << 23);
  for (unsigned i = blockIdx.x * 256 + threadIdx.x; i < n; i += gridDim.x * 256) {
    uint2 e = cb[i];
    float v = __uint_as_float(e.x);
    if (v >= kv) sb[e.y] = v;
  }
}

// ---------------- KFB: dense fallback (flagged samples; pre intact) ----------------
__global__ __launch_bounds__(256, 4) void kfb(float* __restrict__ prespace,
                                              const float* __restrict__ gum,
                                              const float* __restrict__ beta,
                                              const float* __restrict__ kthv,
                                              const unsigned* __restrict__ flags,
                                              const unsigned short* __restrict__ wdb,
                                              const float* __restrict__ b_dec,
                                              float* __restrict__ recon) {
  const int b = blockIdx.z;
  if (!flags[b]) return;
  __shared__ unsigned xsl[64 * 128];
  __shared__ unsigned wtl[64 * 32];
  const int t = threadIdx.x;
  const int pt = blockIdx.x;
  const int p0 = pt << 8;
  const float be = beta[b];
  const float kv = kthv[b];
  const int cg = t >> 5;
  const int pg = t & 31;

  float acc[8][8];
  #pragma unroll
  for (int i = 0; i < 8; i++)
    #pragma unroll
    for (int j = 0; j < 8; j++) acc[i][j] = 0.f;

  for (int tile = 0; tile < 32; ++tile) {
    __syncthreads();
    #pragma unroll
    for (int k = 0; k < 8; ++k) {
      const int ol = 8 * k + (t >> 5);
      const size_t off = (((size_t)(b * HCH + tile * 64 + ol)) << 12) + p0 + ((t & 31) << 3);
      float* pp = prespace + off;
      const float* gp = gum + off;
      float4 pa0 = ((const float4*)pp)[0];
      float4 pa1 = ((const float4*)pp)[1];
      float4 ga0 = ((const float4*)gp)[0];
      float4 ga1 = ((const float4*)gp)[1];
      float4 s0, s1;
      float a;
      a = fmaxf(__fadd_rn(pa0.x, __fmul_rn(be, ga0.x)), 0.f); s0.x = (a >= kv) ? a : 0.f;
      a = fmaxf(__fadd_rn(pa0.y, __fmul_rn(be, ga0.y)), 0.f); s0.y = (a >= kv) ? a : 0.f;
      a = fmaxf(__fadd_rn(pa0.z, __fmul_rn(be, ga0.z)), 0.f); s0.z = (a >= kv) ? a : 0.f;
      a = fmaxf(__fadd_rn(pa0.w, __fmul_rn(be, ga0.w)), 0.f); s0.w = (a >= kv) ? a : 0.f;
      a = fmaxf(__fadd_rn(pa1.x, __fmul_rn(be, ga1.x)), 0.f); s1.x = (a >= kv) ? a : 0.f;
      a = fmaxf(__fadd_rn(pa1.y, __fmul_rn(be, ga1.y)), 0.f); s1.y = (a >= kv) ? a : 0.f;
      a = fmaxf(__fadd_rn(pa1.z, __fmul_rn(be, ga1.z)), 0.f); s1.z = (a >= kv) ? a : 0.f;
      a = fmaxf(__fadd_rn(pa1.w, __fmul_rn(be, ga1.w)), 0.f); s1.w = (a >= kv) ? a : 0.f;
      ((float4*)pp)[0] = s0;
      ((float4*)pp)[1] = s1;
      uint4 pk;
      pk.x = bf16r(s0.x) | (bf16r(s0.y) << 16);
      pk.y = bf16r(s0.z) | (bf16r(s0.w) << 16);
      pk.z = bf16r(s1.x) | (bf16r(s1.y) << 16);
      pk.w = bf16r(s1.z) | (bf16r(s1.w) << 16);
      *(uint4*)&xsl[1024 * k + 4 * t] = pk;
    }
    #pragma unroll
    for (int k = 0; k < 2; ++k) {
      const int ol = 32 * k + (t >> 3);
      const uint4 w = *(const uint4*)(wdb + (((size_t)(tile * 64 + ol)) << 6) + ((t & 7) << 3));
      *(uint4*)&wtl[1024 * k + 4 * t] = w;
    }
    __syncthreads();
    #pragma unroll 8
    for (int cc = 0; cc < 64; ++cc) {
      uint4 xv = *(const uint4*)&xsl[cc * 128 + pg * 4];
      uint4 wv = *(const uint4*)&wtl[cc * 32 + cg * 4];
      float xp[8], wf[8];
      xp[0] = __uint_as_float(xv.x << 16); xp[1] = __uint_as_float(xv.x & 0xffff0000u);
      xp[2] = __uint_as_float(xv.y << 16); xp[3] = __uint_as_float(xv.y & 0xffff0000u);
      xp[4] = __uint_as_float(xv.z << 16); xp[5] = __uint_as_float(xv.z & 0xffff0000u);
      xp[6] = __uint_as_float(xv.w << 16); xp[7] = __uint_as_float(xv.w & 0xffff0000u);
      wf[0] = __uint_as_float(wv.x << 16); wf[1] = __uint_as_float(wv.x & 0xffff0000u);
      wf[2] = __uint_as_float(wv.y << 16); wf[3] = __uint_as_float(wv.y & 0xffff0000u);
      wf[4] = __uint_as_float(wv.z << 16); wf[5] = __uint_as_float(wv.z & 0xffff0000u);
      wf[6] = __uint_as_float(wv.w << 16); wf[7] = __uint_as_float(wv.w & 0xffff0000u);
      #pragma unroll
      for (int i = 0; i < 8; i++)
        #pragma unroll
        for (int j = 0; j < 8; j++)
          acc[i][j] = fmaf(wf[i], xp[j], acc[i][j]);
    }
  }

  #pragma unroll
  for (int i = 0; i < 8; ++i) {
    const int c = cg * 8 + i;
    const float bd = b_dec[c];
    float* pr = recon + (((size_t)(b * NC + c)) << 12) + p0 + pg * 8;
    *(float4*)pr       = make_float4(acc[i][0] + bd, acc[i][1] + bd, acc[i][2] + bd, acc[i][3] + bd);
    *(float4*)(pr + 4) = make_float4(acc[i][4] + bd, acc[i][5] + bd, acc[i][6] + bd, acc[i][7] + bd);
  }
}

extern "C" void kernel_launch(void* const* d_in, const int* in_sizes, int n_in,
                              void* d_out, int out_size, void* d_ws, size_t ws_size,
                              hipStream_t stream) {
  const float* x     = (const float*)d_in[0];
  const float* W     = (const float*)d_in[1];
  const float* b_enc = (const float*)d_in[2];
  const float* b_dec = (const float*)d_in[3];
  const float* gum   = (const float*)d_in[4];
  float* recon  = (float*)d_out;
  float* sparse = recon + RECON_N;   // pre scratch -> buckets -> sparse output

  char* ws = (char*)d_ws;
  uint2*    cand  = (uint2*)(ws + WS_CAND);
  unsigned short* wdb = (unsigned short*)(ws + WS_WD);
  unsigned* ghist = (unsigned*)(ws + WS_GHIST);
  unsigned* mid   = (unsigned*)(ws + WS_MID);
  unsigned* low   = (unsigned*)(ws + WS_LOW);
  double*   part  = (double*)(ws + WS_PART);
  float*    normv = (float*)(ws + WS_NORM);
  float*    beta  = (float*)(ws + WS_BETA);
  unsigned* binT0 = (unsigned*)(ws + WS_BINT0);
  int*      c1v   = (int*)(ws + WS_C1);
  int*      remv  = (int*)(ws + WS_REM);
  int*      c2v   = (int*)(ws + WS_C2);
  int*      rem2v = (int*)(ws + WS_REM2);
  float*    kth   = (float*)(ws + WS_KTH);
  unsigned* flags = (unsigned*)(ws + WS_FLAGS);
  unsigned* gcnt  = (unsigned*)(ws + WS_GCNT);
  unsigned* bcnt  = (unsigned*)(ws + WS_BCNT);
  unsigned* bcnt2 = (unsigned*)(ws + WS_BCNT2);

  hipMemsetAsync(ws + WS_GHIST, 0, 131072, stream);                        // ghist+mid+low
  hipMemsetAsync(ws + WS_FLAGS, 0, WS_BCNT2 + 131072 - WS_FLAGS, stream);  // flags+gcnt+bcnt+bcnt2

  k0a_norm <<<64, 256, 0, stream>>>(W, normv);
  k0b_wd   <<<512, 256, 0, stream>>>(W, normv, wdb);
  k1_encode<<<dim3(32, 16, NB), 256, 0, stream>>>(x, W, b_enc, b_dec, sparse, part);
  k2_beta  <<<NB, 256, 0, stream>>>(part, beta, binT0);
  k3_acts  <<<dim3(1024, 1, NB), 256, 0, stream>>>(sparse, gum, beta, binT0, ghist, cand, gcnt, flags);
  k4a_check<<<NB, 256, 0, stream>>>(ghist, flags);
  k3fb     <<<dim3(1024, 1, NB), 256, 0, stream>>>(sparse, gum, beta, binT0, flags, ghist);
  k4_coarse<<<NB, 256, 0, stream>>>(ghist, c1v, remv, kth);
  k5m      <<<dim3(256, 1, NB), 256, 0, stream>>>(sparse, gum, beta, cand, gcnt, flags, c1v, mid);
  k6a      <<<NB, 256, 0, stream>>>(mid, c1v, remv, c2v, rem2v);
  k5l      <<<dim3(256, 1, NB), 256, 0, stream>>>(sparse, gum, beta, cand, gcnt, flags, c1v, c2v, low);
  k6b      <<<NB, 256, 0, stream>>>(low, c1v, c2v, rem2v, kth);
  kbuck1   <<<dim3(256, 1, NB), 256, 0, stream>>>(cand, gcnt, flags, kth, bcnt);
  kchk     <<<NB, 256, 0, stream>>>(bcnt, flags);
  kbuck2   <<<dim3(256, 1, NB), 256, 0, stream>>>(cand, gcnt, flags, kth, bcnt2, (uint2*)sparse);
  krecon   <<<dim3(1024, 1, NB), 256, 0, stream>>>((const uint2*)sparse, bcnt2, flags, wdb, b_dec, recon);
  kzfill   <<<8192, 256, 0, stream>>>(flags, (float4*)sparse);
  kscat    <<<dim3(256, 1, NB), 256, 0, stream>>>(cand, gcnt, flags, kth, sparse);
  kfb      <<<dim3(16, 1, NB), 256, 0, stream>>>(sparse, gum, beta, kth, flags, wdb, b_dec, recon);
}

// Round 15
// 502.689 us; speedup vs baseline: 1.8613x; 1.1806x over previous
//
#include <hip/hip_runtime.h>
#include <hip/hip_bf16.h>
#include <math.h>

// Problem constants
#define NB    8
#define NC    64
#define HWP   4096          // H*W
#define HCH   2048
#define NSAMP 8388608       // HC*H*W per sample
#define KSEL  167772u       // int(0.02 * NSAMP)
#define RECON_N 2097152     // B*C*H*W
#define CAND_CAP 1048576u   // per-sample candidate capacity (floats)
#define CBUF_CAP 1536u      // per-block LDS candidate buffer (exp ~672, +33 sigma)

// Workspace layout (bytes)
#define WS_CAND   0u          // 33554432: candidates (fp32) -> later 8 bf16 pdec slots (8*RECON_N*2B)
#define WS_WD     33554432u   // wd bf16: 131072 * 2
#define WS_GHIST  33816576u   // 8*2048*4 = 65536
#define WS_MID    33882112u   // 8*1024*4 = 32768
#define WS_LOW    33914880u   // 8*1024*4 = 32768
#define WS_PART   33947648u   // 8*512*2*8 doubles = 65536 (region holds 262144)
#define WS_NORM   34209792u
#define WS_BETA   34210048u
#define WS_BINT0  34210080u
#define WS_C1     34210112u
#define WS_REM    34210144u
#define WS_C2     34210176u
#define WS_REM2   34210208u
#define WS_KTH    34210240u
#define WS_FLAGS  34210304u   // 8*4 flags (bit0: hist insufficiency, bit1: cand overflow)
#define WS_GCNT   34210432u   // 8 counters padded to 128B stride = 1024 bytes

__device__ __forceinline__ unsigned bf16r(float f) {   // RNE round to bf16 (finite inputs)
  unsigned u = __float_as_uint(f);
  unsigned r = (u >> 16) & 1u;
  return (u + 0x7fffu + r) >> 16;
}

// ---------------- K0a: decoder column norms ----------------
__global__ __launch_bounds__(256) void k0a_norm(const float* __restrict__ W,
                                                float* __restrict__ normv) {
  __shared__ float red[256];
  int c = blockIdx.x, t = threadIdx.x;
  float s = 0.f;
  for (int o = t; o < HCH; o += 256) { float w = W[o * NC + c]; s += w * w; }
  red[t] = s; __syncthreads();
  for (int off = 128; off; off >>= 1) { if (t < off) red[t] += red[t + off]; __syncthreads(); }
  if (t == 0) normv[c] = fmaxf(sqrtf(red[0]), 1e-12f);
}

// ---------------- K0b: wdb[o][c] = bf16(W[o][c] / norm[c]) ----------------
__global__ __launch_bounds__(256) void k0b_wd(const float* __restrict__ W,
                                              const float* __restrict__ normv,
                                              unsigned short* __restrict__ wdb) {
  int i = blockIdx.x * 256 + threadIdx.x;
  if (i < HCH * NC) wdb[i] = (unsigned short)bf16r(W[i] / normv[i & 63]);
}

// ---------------- K1b: encode GEMM (128x128 tile, 8x8 micro) + per-block sum/sumsq ----------------
__global__ __launch_bounds__(256) void k1_encode(const float* __restrict__ x,
                                                 const float* __restrict__ W,
                                                 const float* __restrict__ b_enc,
                                                 const float* __restrict__ b_dec,
                                                 float* __restrict__ pre,
                                                 double* __restrict__ part) {
  __shared__ float xs[64][128];   // [c][p]
  __shared__ float wt[64][128];   // [c][o]
  const int t = threadIdx.x;
  const int pt = blockIdx.x;      // 0..31
  const int ot = blockIdx.y;      // 0..15
  const int b  = blockIdx.z;
  const int p0 = pt << 7, o0 = ot << 7;

  {
    const int c  = t >> 2;              // 0..63
    const int pc = (t & 3) << 5;        // 0,32,64,96
    const float* xp = x + (((size_t)(b * NC + c)) << 12) + p0 + pc;
    const float bd = b_dec[c];
    #pragma unroll
    for (int j = 0; j < 8; j++) {
      float4 v = ((const float4*)xp)[j];
      v.x -= bd; v.y -= bd; v.z -= bd; v.w -= bd;
      *(float4*)&xs[c][pc + 4 * j] = v;
    }
    const int ol = t >> 1;              // 0..127
    const int c0 = (t & 1) << 5;        // 0,32
    const float* wp = W + (((size_t)(o0 + ol)) << 6) + c0;
    #pragma unroll
    for (int j = 0; j < 8; j++) {
      float4 w4 = ((const float4*)wp)[j];
      wt[c0 + 4 * j + 0][ol] = w4.x;
      wt[c0 + 4 * j + 1][ol] = w4.y;
      wt[c0 + 4 * j + 2][ol] = w4.z;
      wt[c0 + 4 * j + 3][ol] = w4.w;
    }
  }
  __syncthreads();

  const int og = (t >> 4) << 3;   // 0..120
  const int pg = (t & 15) << 3;   // 0..120
  float acc[8][8];
  #pragma unroll
  for (int i = 0; i < 8; i++)
    #pragma unroll
    for (int j = 0; j < 8; j++) acc[i][j] = 0.f;

  #pragma unroll 8
  for (int cc = 0; cc < 64; cc++) {
    float4 w0 = *(const float4*)&wt[cc][og];
    float4 w1 = *(const float4*)&wt[cc][og + 4];
    float4 x0 = *(const float4*)&xs[cc][pg];
    float4 x1 = *(const float4*)&xs[cc][pg + 4];
    float wv[8] = {w0.x, w0.y, w0.z, w0.w, w1.x, w1.y, w1.z, w1.w};
    float xv[8] = {x0.x, x0.y, x0.z, x0.w, x1.x, x1.y, x1.z, x1.w};
    #pragma unroll
    for (int i = 0; i < 8; i++)
      #pragma unroll
      for (int j = 0; j < 8; j++)
        acc[i][j] += wv[i] * xv[j];
  }

  double s = 0.0, s2 = 0.0;
  #pragma unroll
  for (int i = 0; i < 8; i++) {
    const float be = b_enc[o0 + og + i];
    float r[8];
    #pragma unroll
    for (int j = 0; j < 8; j++) {
      r[j] = acc[i][j] + be;
      double d = (double)r[j];
      s += d; s2 += d * d;
    }
    float* pp = pre + (((size_t)(b * HCH + o0 + og + i)) << 12) + p0 + pg;
    *(float4*)pp       = make_float4(r[0], r[1], r[2], r[3]);
    *(float4*)(pp + 4) = make_float4(r[4], r[5], r[6], r[7]);
  }
  #pragma unroll
  for (int off = 32; off; off >>= 1) { s += __shfl_down(s, off); s2 += __shfl_down(s2, off); }
  __syncthreads();                       // xs no longer read; reuse as redd
  double* redd = (double*)&xs[0][0];
  if ((t & 63) == 0) { redd[(t >> 6) * 2] = s; redd[(t >> 6) * 2 + 1] = s2; }
  __syncthreads();
  if (t == 0) {
    double ts = redd[0] + redd[2] + redd[4] + redd[6];
    double t2 = redd[1] + redd[3] + redd[5] + redd[7];
    int pidx = (b * 16 + ot) * 32 + pt;  // 512 per sample
    part[2 * pidx] = ts; part[2 * pidx + 1] = t2;
  }
}

// ---------------- K2: deterministic reduce -> beta, binT0 ----------------
__global__ __launch_bounds__(256) void k2_beta(const double* __restrict__ part,
                                               float* __restrict__ beta,
                                               unsigned* __restrict__ binT0) {
  __shared__ double sd[256], sd2[256];
  int b = blockIdx.x, t = threadIdx.x;
  double s = 0.0, s2 = 0.0;
  for (int j = 0; j < 2; j++) {
    int pi = b * 512 + t * 2 + j;
    s += part[2 * pi]; s2 += part[2 * pi + 1];
  }
  sd[t] = s; sd2[t] = s2; __syncthreads();
  for (int off = 128; off; off >>= 1) {
    if (t < off) { sd[t] += sd[t + off]; sd2[t] += sd2[t + off]; }
    __syncthreads();
  }
  if (t == 0) {
    const double n = (double)NSAMP;
    double var = (sd2[0] - sd[0] * sd[0] / n) / (n - 1.0);
    if (var < 0.0) var = 0.0;
    float bv = (float)(sqrt(var) * 10.000001);
    beta[b] = bv;
    binT0[b] = __float_as_uint(2.5f * bv) >> 20;   // candidate bin threshold
  }
}

// ---------------- K3: acts + restricted hist + LDS-staged compaction (2x float4 ILP) ----------------
__global__ __launch_bounds__(256) void k3_acts(float* __restrict__ acts,
                                               const float* __restrict__ gum,
                                               const float* __restrict__ beta,
                                               const unsigned* __restrict__ binT0,
                                               unsigned* __restrict__ ghist,
                                               float* __restrict__ cand,
                                               unsigned* __restrict__ gcnt,
                                               unsigned* __restrict__ flags) {
  __shared__ unsigned lh[2048];     // single-copy hist (only ~8% of elems hit it)
  __shared__ float cbuf[CBUF_CAP];  // block-local candidate staging
  __shared__ unsigned lcnt, gbase;
  const int b = blockIdx.z;
  const float be = beta[b];
  const unsigned bT0 = binT0[b];
  const int lane = threadIdx.x & 63;
  const unsigned long long lm_lt = (1ull << lane) - 1ull;
  for (int i = threadIdx.x; i < 2048; i += 256) lh[i] = 0u;
  if (threadIdx.x == 0) lcnt = 0u;
  __syncthreads();
  float4* a4 = (float4*)(acts + ((size_t)b << 23));
  const float4* g4 = (const float4*)(gum + ((size_t)b << 23));
  const int per4 = 1 << 21;
  const int G = gridDim.x * 256;
  for (int i = blockIdx.x * 256 + threadIdx.x; i < per4; i += 2 * G) {
    const int i2 = i + G;                 // grid=1024 -> per4 = 8*G, i2 always < per4
    float4 p0 = a4[i];
    float4 g0 = g4[i];
    float4 p1 = a4[i2];
    float4 g1 = g4[i2];
    float4 A0, A1;
    A0.x = fmaxf(__fadd_rn(p0.x, __fmul_rn(be, g0.x)), 0.f);
    A0.y = fmaxf(__fadd_rn(p0.y, __fmul_rn(be, g0.y)), 0.f);
    A0.z = fmaxf(__fadd_rn(p0.z, __fmul_rn(be, g0.z)), 0.f);
    A0.w = fmaxf(__fadd_rn(p0.w, __fmul_rn(be, g0.w)), 0.f);
    A1.x = fmaxf(__fadd_rn(p1.x, __fmul_rn(be, g1.x)), 0.f);
    A1.y = fmaxf(__fadd_rn(p1.y, __fmul_rn(be, g1.y)), 0.f);
    A1.z = fmaxf(__fadd_rn(p1.z, __fmul_rn(be, g1.z)), 0.f);
    A1.w = fmaxf(__fadd_rn(p1.w, __fmul_rn(be, g1.w)), 0.f);
    a4[i]  = A0;
    a4[i2] = A1;
    // compaction + hist, quad 0
    {
      unsigned u0 = __float_as_uint(A0.x), u1 = __float_as_uint(A0.y);
      unsigned u2 = __float_as_uint(A0.z), u3 = __float_as_uint(A0.w);
      bool c0 = (A0.x > 0.f) && ((u0 >> 20) >= bT0);
      bool c1 = (A0.y > 0.f) && ((u1 >> 20) >= bT0);
      bool c2 = (A0.z > 0.f) && ((u2 >> 20) >= bT0);
      bool c3 = (A0.w > 0.f) && ((u3 >> 20) >= bT0);
      unsigned long long m0 = __ballot(c0), m1 = __ballot(c1);
      unsigned long long m2 = __ballot(c2), m3 = __ballot(c3);
      unsigned n0 = __popcll(m0), n1 = __popcll(m1), n2 = __popcll(m2), n3 = __popcll(m3);
      unsigned tot = n0 + n1 + n2 + n3;
      if (tot) {
        unsigned base = 0;
        if (lane == 0) base = atomicAdd(&lcnt, tot);
        base = (unsigned)__shfl((int)base, 0);
        unsigned i0 = base + __popcll(m0 & lm_lt);
        unsigned i1 = base + n0 + __popcll(m1 & lm_lt);
        unsigned i2a = base + n0 + n1 + __popcll(m2 & lm_lt);
        unsigned i3 = base + n0 + n1 + n2 + __popcll(m3 & lm_lt);
        if (c0 && i0 < CBUF_CAP) cbuf[i0] = A0.x;
        if (c1 && i1 < CBUF_CAP) cbuf[i1] = A0.y;
        if (c2 && i2a < CBUF_CAP) cbuf[i2a] = A0.z;
        if (c3 && i3 < CBUF_CAP) cbuf[i3] = A0.w;
        if (c0) atomicAdd(&lh[u0 >> 20], 1u);
        if (c1) atomicAdd(&lh[u1 >> 20], 1u);
        if (c2) atomicAdd(&lh[u2 >> 20], 1u);
        if (c3) atomicAdd(&lh[u3 >> 20], 1u);
      }
    }
    // compaction + hist, quad 1
    {
      unsigned u0 = __float_as_uint(A1.x), u1 = __float_as_uint(A1.y);
      unsigned u2 = __float_as_uint(A1.z), u3 = __float_as_uint(A1.w);
      bool c0 = (A1.x > 0.f) && ((u0 >> 20) >= bT0);
      bool c1 = (A1.y > 0.f) && ((u1 >> 20) >= bT0);
      bool c2 = (A1.z > 0.f) && ((u2 >> 20) >= bT0);
      bool c3 = (A1.w > 0.f) && ((u3 >> 20) >= bT0);
      unsigned long long m0 = __ballot(c0), m1 = __ballot(c1);
      unsigned long long m2 = __ballot(c2), m3 = __ballot(c3);
      unsigned n0 = __popcll(m0), n1 = __popcll(m1), n2 = __popcll(m2), n3 = __popcll(m3);
      unsigned tot = n0 + n1 + n2 + n3;
      if (tot) {
        unsigned base = 0;
        if (lane == 0) base = atomicAdd(&lcnt, tot);
        base = (unsigned)__shfl((int)base, 0);
        unsigned i0 = base + __popcll(m0 & lm_lt);
        unsigned i1 = base + n0 + __popcll(m1 & lm_lt);
        unsigned i2a = base + n0 + n1 + __popcll(m2 & lm_lt);
        unsigned i3 = base + n0 + n1 + n2 + __popcll(m3 & lm_lt);
        if (c0 && i0 < CBUF_CAP) cbuf[i0] = A1.x;
        if (c1 && i1 < CBUF_CAP) cbuf[i1] = A1.y;
        if (c2 && i2a < CBUF_CAP) cbuf[i2a] = A1.z;
        if (c3 && i3 < CBUF_CAP) cbuf[i3] = A1.w;
        if (c0) atomicAdd(&lh[u0 >> 20], 1u);
        if (c1) atomicAdd(&lh[u1 >> 20], 1u);
        if (c2) atomicAdd(&lh[u2 >> 20], 1u);
        if (c3) atomicAdd(&lh[u3 >> 20], 1u);
      }
    }
  }
  __syncthreads();
  if (threadIdx.x == 0) {
    unsigned n = lcnt;
    if (n > CBUF_CAP) { atomicOr(&flags[b], 2u); n = CBUF_CAP; }
    unsigned gb = atomicAdd(&gcnt[b * 32], n);
    if (gb + n > CAND_CAP) atomicOr(&flags[b], 2u);
    gbase = gb;
  }
  __syncthreads();
  {
    float* candb = cand + ((size_t)b * CAND_CAP);
    const unsigned n = (lcnt > CBUF_CAP) ? CBUF_CAP : lcnt;
    const unsigned gb = gbase;
    for (unsigned i = threadIdx.x; i < n; i += 256) {
      unsigned d = gb + i;
      if (d < CAND_CAP) candb[d] = cbuf[i];
    }
  }
  for (int i = threadIdx.x; i < 2048; i += 256) {
    unsigned v = lh[i];
    if (v) atomicAdd(&ghist[(b << 11) + i], v);
  }
}

// ---------------- K4a: check restricted-hist sufficiency ----------------
__global__ __launch_bounds__(256) void k4a_check(const unsigned* __restrict__ ghist,
                                                 unsigned* __restrict__ flags) {
  __shared__ unsigned red[256];
  int b = blockIdx.x, t = threadIdx.x;
  unsigned s = 0;
  for (int j = 0; j < 8; j++) s += ghist[(b << 11) + t * 8 + j];
  red[t] = s; __syncthreads();
  for (int off = 128; off; off >>= 1) { if (t < off) red[t] += red[t + off]; __syncthreads(); }
  if (t == 0 && red[0] < KSEL) atomicOr(&flags[b], 1u);
}

// ---------------- K3fb: fallback full histogram of bins < binT0 (early-exit) ----------------
__global__ __launch_bounds__(256) void k3fb(const float* __restrict__ acts,
                                            const unsigned* __restrict__ binT0,
                                            const unsigned* __restrict__ flags,
                                            unsigned* __restrict__ ghist) {
  const int b = blockIdx.z;
  if ((flags[b] & 1u) == 0u) return;
  __shared__ unsigned lh[8192];
  const unsigned bT0 = binT0[b];
  const unsigned sub = threadIdx.x & 3;
  for (int i = threadIdx.x; i < 8192; i += 256) lh[i] = 0u;
  __syncthreads();
  const float4* a4 = (const float4*)(acts + ((size_t)b << 23));
  const int per4 = 1 << 21;
  for (int i = blockIdx.x * 256 + threadIdx.x; i < per4; i += gridDim.x * 256) {
    float4 a = a4[i];
    unsigned u;
    u = __float_as_uint(a.x);
    if (a.x > 0.f && (u >> 20) < bT0) atomicAdd(&lh[((u >> 20) << 2) | sub], 1u);
    u = __float_as_uint(a.y);
    if (a.y > 0.f && (u >> 20) < bT0) atomicAdd(&lh[((u >> 20) << 2) | sub], 1u);
    u = __float_as_uint(a.z);
    if (a.z > 0.f && (u >> 20) < bT0) atomicAdd(&lh[((u >> 20) << 2) | sub], 1u);
    u = __float_as_uint(a.w);
    if (a.w > 0.f && (u >> 20) < bT0) atomicAdd(&lh[((u >> 20) << 2) | sub], 1u);
  }
  __syncthreads();
  for (int i = threadIdx.x; i < 2048; i += 256) {
    unsigned v = lh[4 * i] + lh[4 * i + 1] + lh[4 * i + 2] + lh[4 * i + 3];
    if (v) atomicAdd(&ghist[(b << 11) + i], v);
  }
}

// ---------------- K4: pick coarse bin + remaining count ----------------
__global__ __launch_bounds__(256) void k4_coarse(const unsigned* __restrict__ ghist,
                                                 int* __restrict__ c1v,
                                                 int* __restrict__ remv,
                                                 float* __restrict__ kth) {
  __shared__ unsigned h[2048];
  __shared__ unsigned csum[256];
  int b = blockIdx.x, t = threadIdx.x;
  for (int i = t; i < 2048; i += 256) h[i] = ghist[(b << 11) + i];
  __syncthreads();
  unsigned cs = 0;
  for (int j = 0; j < 8; j++) cs += h[t * 8 + j];
  csum[t] = cs; __syncthreads();
  unsigned suf = 0;
  for (int tt = t + 1; tt < 256; tt++) suf += csum[tt];
  if (suf < KSEL && suf + cs >= KSEL) {
    unsigned cum = suf;
    for (int j = 7; j >= 0; j--) {
      unsigned hv = h[t * 8 + j];
      cum += hv;
      if (cum >= KSEL) { c1v[b] = t * 8 + j; remv[b] = (int)(KSEL - (cum - hv)); break; }
    }
  }
  if (t == 0) {
    unsigned tot = 0;
    for (int tt = 0; tt < 256; tt++) tot += csum[tt];
    if (tot < KSEL) { c1v[b] = -1; kth[b] = 0.f; }
  }
}

// ---------------- K5m: mid histogram (bits 19:10) within c1 ----------------
__global__ __launch_bounds__(256) void k5m(const float* __restrict__ acts,
                                           const float* __restrict__ cand,
                                           const unsigned* __restrict__ gcnt,
                                           const unsigned* __restrict__ flags,
                                           const int* __restrict__ c1v,
                                           unsigned* __restrict__ mid) {
  const int b = blockIdx.z;
  const int c1 = c1v[b];
  __shared__ unsigned lm[1024];
  for (int i = threadIdx.x; i < 1024; i += 256) lm[i] = 0u;
  __syncthreads();
  if (c1 >= 0) {
    const unsigned c1u = (unsigned)c1;
    if (flags[b] == 0u) {
      const float* candb = cand + ((size_t)b * CAND_CAP);
      const unsigned n = gcnt[b * 32];
      for (unsigned i = blockIdx.x * 256 + threadIdx.x; i < n; i += gridDim.x * 256) {
        unsigned u = __float_as_uint(candb[i]);
        if ((u >> 20) == c1u) atomicAdd(&lm[(u >> 10) & 0x3FFu], 1u);
      }
    } else {
      const float4* a4 = (const float4*)(acts + ((size_t)b << 23));
      for (int i = blockIdx.x * 256 + threadIdx.x; i < (1 << 21); i += gridDim.x * 256) {
        float4 a = a4[i];
        unsigned u;
        u = __float_as_uint(a.x);
        if (a.x > 0.f && (u >> 20) == c1u) atomicAdd(&lm[(u >> 10) & 0x3FFu], 1u);
        u = __float_as_uint(a.y);
        if (a.y > 0.f && (u >> 20) == c1u) atomicAdd(&lm[(u >> 10) & 0x3FFu], 1u);
        u = __float_as_uint(a.z);
        if (a.z > 0.f && (u >> 20) == c1u) atomicAdd(&lm[(u >> 10) & 0x3FFu], 1u);
        u = __float_as_uint(a.w);
        if (a.w > 0.f && (u >> 20) == c1u) atomicAdd(&lm[(u >> 10) & 0x3FFu], 1u);
      }
    }
  }
  __syncthreads();
  for (int i = threadIdx.x; i < 1024; i += 256) {
    unsigned v = lm[i];
    if (v) atomicAdd(&mid[(b << 10) + i], v);
  }
}

// ---------------- K6a: pick c2 + rem2 ----------------
__global__ __launch_bounds__(256) void k6a(const unsigned* __restrict__ mid,
                                           const int* __restrict__ c1v,
                                           const int* __restrict__ remv,
                                           int* __restrict__ c2v,
                                           int* __restrict__ rem2v) {
  int b = blockIdx.x, t = threadIdx.x;
  if (c1v[b] < 0) return;
  __shared__ unsigned h[1024];
  __shared__ unsigned csum[256];
  for (int i = t; i < 1024; i += 256) h[i] = mid[(b << 10) + i];
  __syncthreads();
  unsigned cs = 0;
  for (int j = 0; j < 4; j++) cs += h[t * 4 + j];
  csum[t] = cs; __syncthreads();
  unsigned suf = 0;
  for (int tt = t + 1; tt < 256; tt++) suf += csum[tt];
  unsigned R = (unsigned)remv[b];
  if (suf < R && suf + cs >= R) {
    unsigned cum = suf;
    for (int j = 3; j >= 0; j--) {
      unsigned hv = h[t * 4 + j];
      cum += hv;
      if (cum >= R) { c2v[b] = t * 4 + j; rem2v[b] = (int)(R - (cum - hv)); break; }
    }
  }
}

// ---------------- K5l: low histogram (bits 9:0) within (c1,c2) ----------------
__global__ __launch_bounds__(256) void k5l(const float* __restrict__ acts,
                                           const float* __restrict__ cand,
                                           const unsigned* __restrict__ gcnt,
                                           const unsigned* __restrict__ flags,
                                           const int* __restrict__ c1v,
                                           const int* __restrict__ c2v,
                                           unsigned* __restrict__ low) {
  const int b = blockIdx.z;
  const int c1 = c1v[b];
  __shared__ unsigned lm[1024];
  for (int i = threadIdx.x; i < 1024; i += 256) lm[i] = 0u;
  __syncthreads();
  if (c1 >= 0) {
    const unsigned key = ((unsigned)c1 << 10) | (unsigned)c2v[b];   // compare vs u>>10
    if (flags[b] == 0u) {
      const float* candb = cand + ((size_t)b * CAND_CAP);
      const unsigned n = gcnt[b * 32];
      for (unsigned i = blockIdx.x * 256 + threadIdx.x; i < n; i += gridDim.x * 256) {
        unsigned u = __float_as_uint(candb[i]);
        if ((u >> 10) == key) atomicAdd(&lm[u & 0x3FFu], 1u);
      }
    } else {
      const float4* a4 = (const float4*)(acts + ((size_t)b << 23));
      for (int i = blockIdx.x * 256 + threadIdx.x; i < (1 << 21); i += gridDim.x * 256) {
        float4 a = a4[i];
        unsigned u;
        u = __float_as_uint(a.x);
        if (a.x > 0.f && (u >> 10) == key) atomicAdd(&lm[u & 0x3FFu], 1u);
        u = __float_as_uint(a.y);
        if (a.y > 0.f && (u >> 10) == key) atomicAdd(&lm[u & 0x3FFu], 1u);
        u = __float_as_uint(a.z);
        if (a.z > 0.f && (u >> 10) == key) atomicAdd(&lm[u & 0x3FFu], 1u);
        u = __float_as_uint(a.w);
        if (a.w > 0.f && (u >> 10) == key) atomicAdd(&lm[u & 0x3FFu], 1u);
      }
    }
  }
  __syncthreads();
  for (int i = threadIdx.x; i < 1024; i += 256) {
    unsigned v = lm[i];
    if (v) atomicAdd(&low[(b << 10) + i], v);
  }
}

// ---------------- K6b: exact kth value ----------------
__global__ __launch_bounds__(256) void k6b(const unsigned* __restrict__ low,
                                           const int* __restrict__ c1v,
                                           const int* __restrict__ c2v,
                                           const int* __restrict__ rem2v,
                                           float* __restrict__ kth) {
  int b = blockIdx.x, t = threadIdx.x;
  int c1 = c1v[b];
  if (c1 < 0) return;
  __shared__ unsigned h[1024];
  __shared__ unsigned csum[256];
  for (int i = t; i < 1024; i += 256) h[i] = low[(b << 10) + i];
  __syncthreads();
  unsigned cs = 0;
  for (int j = 0; j < 4; j++) cs += h[t * 4 + j];
  csum[t] = cs; __syncthreads();
  unsigned suf = 0;
  for (int tt = t + 1; tt < 256; tt++) suf += csum[tt];
  unsigned R2 = (unsigned)rem2v[b];
  if (suf < R2 && suf + cs >= R2) {
    unsigned cum = suf;
    for (int j = 3; j >= 0; j--) {
      unsigned hv = h[t * 4 + j];
      cum += hv;
      if (cum >= R2) {
        unsigned bits = ((unsigned)c1 << 20) | ((unsigned)c2v[b] << 10) | (unsigned)(t * 4 + j);
        kth[b] = __uint_as_float(bits);
        break;
      }
    }
  }
}

// ---------------- K7g: mask + sparse write + decode GEMM (bf16 LDS, 8x8 micro, kc=8, bf16 partials) ----------------
__global__ __launch_bounds__(256, 4) void k7g_decode(float* __restrict__ acts,
                                                     const unsigned short* __restrict__ wdb,
                                                     const float* __restrict__ kthv,
                                                     unsigned short* __restrict__ pdec) {
  __shared__ unsigned xsl[64 * 128];   // [o][p-pair] 32KB
  __shared__ unsigned wtl[64 * 32];    // [o][c-pair] 8KB
  const int t = threadIdx.x;
  const int pt = blockIdx.x;           // 0..15
  const int kc = blockIdx.y;           // 0..7
  const int b  = blockIdx.z;
  const int p0 = pt << 8;
  const float kth = kthv[b];
  const int cg = t >> 5;               // 0..7 -> c0 = cg*8
  const int pg = t & 31;               // p-group -> p = p0 + pg*8
  const int ob0 = kc * 256;

  float acc[8][8];
  #pragma unroll
  for (int i = 0; i < 8; i++)
    #pragma unroll
    for (int j = 0; j < 8; j++) acc[i][j] = 0.f;

  for (int tile = 0; tile < 4; ++tile) {
    __syncthreads();
    #pragma unroll
    for (int k = 0; k < 8; ++k) {
      const int ol = 8 * k + (t >> 5);
      float* ap = acts + (((size_t)(b * HCH + ob0 + tile * 64 + ol)) << 12) + p0 + ((t & 31) << 3);
      float4 a0 = ((const float4*)ap)[0];
      float4 a1 = ((const float4*)ap)[1];
      float4 s0, s1;
      s0.x = (a0.x >= kth) ? a0.x : 0.f;  s0.y = (a0.y >= kth) ? a0.y : 0.f;
      s0.z = (a0.z >= kth) ? a0.z : 0.f;  s0.w = (a0.w >= kth) ? a0.w : 0.f;
      s1.x = (a1.x >= kth) ? a1.x : 0.f;  s1.y = (a1.y >= kth) ? a1.y : 0.f;
      s1.z = (a1.z >= kth) ? a1.z : 0.f;  s1.w = (a1.w >= kth) ? a1.w : 0.f;
      ((float4*)ap)[0] = s0;
      ((float4*)ap)[1] = s1;
      uint4 pk;
      pk.x = bf16r(s0.x) | (bf16r(s0.y) << 16);
      pk.y = bf16r(s0.z) | (bf16r(s0.w) << 16);
      pk.z = bf16r(s1.x) | (bf16r(s1.y) << 16);
      pk.w = bf16r(s1.z) | (bf16r(s1.w) << 16);
      *(uint4*)&xsl[1024 * k + 4 * t] = pk;
    }
    #pragma unroll
    for (int k = 0; k < 2; ++k) {
      const int ol = 32 * k + (t >> 3);
      const uint4 w = *(const uint4*)(wdb + (((size_t)(ob0 + tile * 64 + ol)) << 6) + ((t & 7) << 3));
      *(uint4*)&wtl[1024 * k + 4 * t] = w;
    }
    __syncthreads();
    #pragma unroll 8
    for (int cc = 0; cc < 64; ++cc) {
      uint4 xv = *(const uint4*)&xsl[cc * 128 + pg * 4];
      uint4 wv = *(const uint4*)&wtl[cc * 32 + cg * 4];
      float xp[8], wf[8];
      xp[0] = __uint_as_float(xv.x << 16); xp[1] = __uint_as_float(xv.x & 0xffff0000u);
      xp[2] = __uint_as_float(xv.y << 16); xp[3] = __uint_as_float(xv.y & 0xffff0000u);
      xp[4] = __uint_as_float(xv.z << 16); xp[5] = __uint_as_float(xv.z & 0xffff0000u);
      xp[6] = __uint_as_float(xv.w << 16); xp[7] = __uint_as_float(xv.w & 0xffff0000u);
      wf[0] = __uint_as_float(wv.x << 16); wf[1] = __uint_as_float(wv.x & 0xffff0000u);
      wf[2] = __uint_as_float(wv.y << 16); wf[3] = __uint_as_float(wv.y & 0xffff0000u);
      wf[4] = __uint_as_float(wv.z << 16); wf[5] = __uint_as_float(wv.z & 0xffff0000u);
      wf[6] = __uint_as_float(wv.w << 16); wf[7] = __uint_as_float(wv.w & 0xffff0000u);
      #pragma unroll
      for (int i = 0; i < 8; i++)
        #pragma unroll
        for (int j = 0; j < 8; j++)
          acc[i][j] = fmaf(wf[i], xp[j], acc[i][j]);
    }
  }

  // write bf16 partial tile to slot kc (each address written exactly once)
  unsigned short* pb = pdec + (size_t)kc * RECON_N + (((size_t)(b * NC)) << 12) + p0 + pg * 8;
  #pragma unroll
  for (int i = 0; i < 8; ++i) {
    unsigned short* pr = pb + ((size_t)(cg * 8 + i) << 12);
    uint4 w;
    w.x = bf16r(acc[i][0]) | (bf16r(acc[i][1]) << 16);
    w.y = bf16r(acc[i][2]) | (bf16r(acc[i][3]) << 16);
    w.z = bf16r(acc[i][4]) | (bf16r(acc[i][5]) << 16);
    w.w = bf16r(acc[i][6]) | (bf16r(acc[i][7]) << 16);
    *(uint4*)pr = w;
  }
}

// ---------------- K8: recon = sum of 8 bf16 partial slots + b_dec ----------------
__global__ __launch_bounds__(256) void k8_add(const unsigned short* __restrict__ pdec,
                                              const float* __restrict__ b_dec,
                                              float* __restrict__ recon) {
  const int i = blockIdx.x * 256 + threadIdx.x;   // over RECON_N/4 groups of 4
  if (i < (RECON_N / 4)) {
    const uint2* ps = (const uint2*)pdec;          // 4 bf16 per uint2
    float r0 = 0.f, r1 = 0.f, r2 = 0.f, r3 = 0.f;
    #pragma unroll
    for (int s = 0; s < 8; ++s) {
      uint2 v = ps[(size_t)s * (RECON_N / 4) + i];
      r0 += __uint_as_float(v.x << 16);
      r1 += __uint_as_float(v.x & 0xffff0000u);
      r2 += __uint_as_float(v.y << 16);
      r3 += __uint_as_float(v.y & 0xffff0000u);
    }
    const float bd = b_dec[(i >> 10) & 63];
    ((float4*)recon)[i] = make_float4(r0 + bd, r1 + bd, r2 + bd, r3 + bd);
  }
}

extern "C" void kernel_launch(void* const* d_in, const int* in_sizes, int n_in,
                              void* d_out, int out_size, void* d_ws, size_t ws_size,
                              hipStream_t stream) {
  const float* x     = (const float*)d_in[0];
  const float* W     = (const float*)d_in[1];
  const float* b_enc = (const float*)d_in[2];
  const float* b_dec = (const float*)d_in[3];
  const float* gum   = (const float*)d_in[4];
  float* recon  = (float*)d_out;
  float* sparse = recon + RECON_N;   // pre/acts scratch

  char* ws = (char*)d_ws;
  float*    cand  = (float*)(ws + WS_CAND);
  unsigned short* pdec = (unsigned short*)(ws + WS_CAND);  // reuse after k6b (no zeroing needed)
  unsigned short* wdb = (unsigned short*)(ws + WS_WD);
  unsigned* ghist = (unsigned*)(ws + WS_GHIST);
  unsigned* mid   = (unsigned*)(ws + WS_MID);
  unsigned* low   = (unsigned*)(ws + WS_LOW);
  double*   part  = (double*)(ws + WS_PART);
  float*    normv = (float*)(ws + WS_NORM);
  float*    beta  = (float*)(ws + WS_BETA);
  unsigned* binT0 = (unsigned*)(ws + WS_BINT0);
  int*      c1v   = (int*)(ws + WS_C1);
  int*      remv  = (int*)(ws + WS_REM);
  int*      c2v   = (int*)(ws + WS_C2);
  int*      rem2v = (int*)(ws + WS_REM2);
  float*    kth   = (float*)(ws + WS_KTH);
  unsigned* flags = (unsigned*)(ws + WS_FLAGS);
  unsigned* gcnt  = (unsigned*)(ws + WS_GCNT);

  hipMemsetAsync(ws + WS_GHIST, 0, 131072, stream);    // ghist+mid+low
  hipMemsetAsync(ws + WS_FLAGS, 0, 1152, stream);      // flags + padded gcnt

  k0a_norm  <<<64, 256, 0, stream>>>(W, normv);
  k0b_wd    <<<512, 256, 0, stream>>>(W, normv, wdb);
  k1_encode <<<dim3(32, 16, NB), 256, 0, stream>>>(x, W, b_enc, b_dec, sparse, part);
  k2_beta   <<<NB, 256, 0, stream>>>(part, beta, binT0);
  k3_acts   <<<dim3(1024, 1, NB), 256, 0, stream>>>(sparse, gum, beta, binT0, ghist, cand, gcnt, flags);
  k4a_check <<<NB, 256, 0, stream>>>(ghist, flags);
  k3fb      <<<dim3(1024, 1, NB), 256, 0, stream>>>(sparse, binT0, flags, ghist);
  k4_coarse <<<NB, 256, 0, stream>>>(ghist, c1v, remv, kth);
  k5m       <<<dim3(256, 1, NB), 256, 0, stream>>>(sparse, cand, gcnt, flags, c1v, mid);
  k6a       <<<NB, 256, 0, stream>>>(mid, c1v, remv, c2v, rem2v);
  k5l       <<<dim3(256, 1, NB), 256, 0, stream>>>(sparse, cand, gcnt, flags, c1v, c2v, low);
  k6b       <<<NB, 256, 0, stream>>>(low, c1v, c2v, rem2v, kth);
  k7g_decode<<<dim3(16, 8, NB), 256, 0, stream>>>(sparse, wdb, kth, pdec);
  k8_add    <<<RECON_N / 4 / 256, 256, 0, stream>>>(pdec, b_dec, recon);
}

// Round 16
// 474.611 us; speedup vs baseline: 1.9714x; 1.0592x over previous
//
#include <hip/hip_runtime.h>
#include <hip/hip_bf16.h>
#include <math.h>

// Problem constants
#define NB    8
#define NC    64
#define HWP   4096          // H*W
#define HCH   2048
#define NSAMP 8388608       // HC*H*W per sample
#define KSEL  167772u       // int(0.02 * NSAMP)
#define RECON_N 2097152     // B*C*H*W
#define CAND_CAP 1048576u   // per-sample candidate capacity (floats)
#define CBUF_CAP 1536u      // per-block LDS candidate buffer (exp ~672, +33 sigma)

// Workspace layout (bytes)
#define WS_CAND   0u          // 33554432: candidates (fp32) -> later 8 bf16 pdec slots (8*RECON_N*2B)
#define WS_WD     33554432u   // wd bf16: 131072 * 2
#define WS_GHIST  33816576u   // 8*2048*4 = 65536
#define WS_MID    33882112u   // 8*1024*4 = 32768
#define WS_LOW    33914880u   // 8*1024*4 = 32768
#define WS_PART   33947648u   // 8*512*2*8 doubles = 65536 (region holds 262144)
#define WS_NORM   34209792u
#define WS_BETA   34210048u
#define WS_BINT0  34210080u
#define WS_C1     34210112u
#define WS_REM    34210144u
#define WS_C2     34210176u
#define WS_REM2   34210208u
#define WS_KTH    34210240u
#define WS_FLAGS  34210304u   // 8*4 flags (bit0: hist insufficiency, bit1: cand overflow)
#define WS_GCNT   34210432u   // 8 counters padded to 128B stride = 1024 bytes

typedef float f4 __attribute__((ext_vector_type(4)));

__device__ __forceinline__ unsigned bf16r(float f) {   // RNE round to bf16 (finite inputs)
  unsigned u = __float_as_uint(f);
  unsigned r = (u >> 16) & 1u;
  return (u + 0x7fffu + r) >> 16;
}

// ---------------- K0a: decoder column norms ----------------
__global__ __launch_bounds__(256) void k0a_norm(const float* __restrict__ W,
                                                float* __restrict__ normv) {
  __shared__ float red[256];
  int c = blockIdx.x, t = threadIdx.x;
  float s = 0.f;
  for (int o = t; o < HCH; o += 256) { float w = W[o * NC + c]; s += w * w; }
  red[t] = s; __syncthreads();
  for (int off = 128; off; off >>= 1) { if (t < off) red[t] += red[t + off]; __syncthreads(); }
  if (t == 0) normv[c] = fmaxf(sqrtf(red[0]), 1e-12f);
}

// ---------------- K0b: wdb[o][c] = bf16(W[o][c] / norm[c]) ----------------
__global__ __launch_bounds__(256) void k0b_wd(const float* __restrict__ W,
                                              const float* __restrict__ normv,
                                              unsigned short* __restrict__ wdb) {
  int i = blockIdx.x * 256 + threadIdx.x;
  if (i < HCH * NC) wdb[i] = (unsigned short)bf16r(W[i] / normv[i & 63]);
}

// ---------------- K1b: encode GEMM (128x128 tile, 8x8 micro) + per-block sum/sumsq ----------------
__global__ __launch_bounds__(256) void k1_encode(const float* __restrict__ x,
                                                 const float* __restrict__ W,
                                                 const float* __restrict__ b_enc,
                                                 const float* __restrict__ b_dec,
                                                 float* __restrict__ pre,
                                                 double* __restrict__ part) {
  __shared__ float xs[64][128];   // [c][p]
  __shared__ float wt[64][128];   // [c][o]
  const int t = threadIdx.x;
  const int pt = blockIdx.x;      // 0..31
  const int ot = blockIdx.y;      // 0..15
  const int b  = blockIdx.z;
  const int p0 = pt << 7, o0 = ot << 7;

  {
    const int c  = t >> 2;              // 0..63
    const int pc = (t & 3) << 5;        // 0,32,64,96
    const float* xp = x + (((size_t)(b * NC + c)) << 12) + p0 + pc;
    const float bd = b_dec[c];
    #pragma unroll
    for (int j = 0; j < 8; j++) {
      float4 v = ((const float4*)xp)[j];
      v.x -= bd; v.y -= bd; v.z -= bd; v.w -= bd;
      *(float4*)&xs[c][pc + 4 * j] = v;
    }
    const int ol = t >> 1;              // 0..127
    const int c0 = (t & 1) << 5;        // 0,32
    const float* wp = W + (((size_t)(o0 + ol)) << 6) + c0;
    #pragma unroll
    for (int j = 0; j < 8; j++) {
      float4 w4 = ((const float4*)wp)[j];
      wt[c0 + 4 * j + 0][ol] = w4.x;
      wt[c0 + 4 * j + 1][ol] = w4.y;
      wt[c0 + 4 * j + 2][ol] = w4.z;
      wt[c0 + 4 * j + 3][ol] = w4.w;
    }
  }
  __syncthreads();

  const int og = (t >> 4) << 3;   // 0..120
  const int pg = (t & 15) << 3;   // 0..120
  float acc[8][8];
  #pragma unroll
  for (int i = 0; i < 8; i++)
    #pragma unroll
    for (int j = 0; j < 8; j++) acc[i][j] = 0.f;

  #pragma unroll 8
  for (int cc = 0; cc < 64; cc++) {
    float4 w0 = *(const float4*)&wt[cc][og];
    float4 w1 = *(const float4*)&wt[cc][og + 4];
    float4 x0 = *(const float4*)&xs[cc][pg];
    float4 x1 = *(const float4*)&xs[cc][pg + 4];
    float wv[8] = {w0.x, w0.y, w0.z, w0.w, w1.x, w1.y, w1.z, w1.w};
    float xv[8] = {x0.x, x0.y, x0.z, x0.w, x1.x, x1.y, x1.z, x1.w};
    #pragma unroll
    for (int i = 0; i < 8; i++)
      #pragma unroll
      for (int j = 0; j < 8; j++)
        acc[i][j] += wv[i] * xv[j];
  }

  double s = 0.0, s2 = 0.0;
  #pragma unroll
  for (int i = 0; i < 8; i++) {
    const float be = b_enc[o0 + og + i];
    float r[8];
    #pragma unroll
    for (int j = 0; j < 8; j++) {
      r[j] = acc[i][j] + be;
      double d = (double)r[j];
      s += d; s2 += d * d;
    }
    float* pp = pre + (((size_t)(b * HCH + o0 + og + i)) << 12) + p0 + pg;
    *(float4*)pp       = make_float4(r[0], r[1], r[2], r[3]);
    *(float4*)(pp + 4) = make_float4(r[4], r[5], r[6], r[7]);
  }
  #pragma unroll
  for (int off = 32; off; off >>= 1) { s += __shfl_down(s, off); s2 += __shfl_down(s2, off); }
  __syncthreads();                       // xs no longer read; reuse as redd
  double* redd = (double*)&xs[0][0];
  if ((t & 63) == 0) { redd[(t >> 6) * 2] = s; redd[(t >> 6) * 2 + 1] = s2; }
  __syncthreads();
  if (t == 0) {
    double ts = redd[0] + redd[2] + redd[4] + redd[6];
    double t2 = redd[1] + redd[3] + redd[5] + redd[7];
    int pidx = (b * 16 + ot) * 32 + pt;  // 512 per sample
    part[2 * pidx] = ts; part[2 * pidx + 1] = t2;
  }
}

// ---------------- K2: deterministic reduce -> beta, binT0 ----------------
__global__ __launch_bounds__(256) void k2_beta(const double* __restrict__ part,
                                               float* __restrict__ beta,
                                               unsigned* __restrict__ binT0) {
  __shared__ double sd[256], sd2[256];
  int b = blockIdx.x, t = threadIdx.x;
  double s = 0.0, s2 = 0.0;
  for (int j = 0; j < 2; j++) {
    int pi = b * 512 + t * 2 + j;
    s += part[2 * pi]; s2 += part[2 * pi + 1];
  }
  sd[t] = s; sd2[t] = s2; __syncthreads();
  for (int off = 128; off; off >>= 1) {
    if (t < off) { sd[t] += sd[t + off]; sd2[t] += sd2[t + off]; }
    __syncthreads();
  }
  if (t == 0) {
    const double n = (double)NSAMP;
    double var = (sd2[0] - sd[0] * sd[0] / n) / (n - 1.0);
    if (var < 0.0) var = 0.0;
    float bv = (float)(sqrt(var) * 10.000001);
    beta[b] = bv;
    binT0[b] = __float_as_uint(2.5f * bv) >> 20;   // candidate bin threshold
  }
}

// ---------------- K3: acts + restricted hist + LDS-staged compaction (NT gum loads) ----------------
__global__ __launch_bounds__(256) void k3_acts(float* __restrict__ acts,
                                               const float* __restrict__ gum,
                                               const float* __restrict__ beta,
                                               const unsigned* __restrict__ binT0,
                                               unsigned* __restrict__ ghist,
                                               float* __restrict__ cand,
                                               unsigned* __restrict__ gcnt,
                                               unsigned* __restrict__ flags) {
  __shared__ unsigned lh[2048];     // single-copy hist (only ~8% of elems hit it)
  __shared__ float cbuf[CBUF_CAP];  // block-local candidate staging
  __shared__ unsigned lcnt, gbase;
  const int b = blockIdx.z;
  const float be = beta[b];
  const unsigned bT0 = binT0[b];
  const int lane = threadIdx.x & 63;
  const unsigned long long lm_lt = (1ull << lane) - 1ull;
  for (int i = threadIdx.x; i < 2048; i += 256) lh[i] = 0u;
  if (threadIdx.x == 0) lcnt = 0u;
  __syncthreads();
  float4* a4 = (float4*)(acts + ((size_t)b << 23));
  const f4* g4 = (const f4*)(gum + ((size_t)b << 23));
  const int per4 = 1 << 21;
  const int G = gridDim.x * 256;
  for (int i = blockIdx.x * 256 + threadIdx.x; i < per4; i += 2 * G) {
    const int i2 = i + G;                 // grid=1024 -> per4 = 8*G, i2 always < per4
    float4 p0 = a4[i];
    f4 g0 = __builtin_nontemporal_load(g4 + i);    // gum read once -> don't pollute L3
    float4 p1 = a4[i2];
    f4 g1 = __builtin_nontemporal_load(g4 + i2);
    float4 A0, A1;
    A0.x = fmaxf(__fadd_rn(p0.x, __fmul_rn(be, g0.x)), 0.f);
    A0.y = fmaxf(__fadd_rn(p0.y, __fmul_rn(be, g0.y)), 0.f);
    A0.z = fmaxf(__fadd_rn(p0.z, __fmul_rn(be, g0.z)), 0.f);
    A0.w = fmaxf(__fadd_rn(p0.w, __fmul_rn(be, g0.w)), 0.f);
    A1.x = fmaxf(__fadd_rn(p1.x, __fmul_rn(be, g1.x)), 0.f);
    A1.y = fmaxf(__fadd_rn(p1.y, __fmul_rn(be, g1.y)), 0.f);
    A1.z = fmaxf(__fadd_rn(p1.z, __fmul_rn(be, g1.z)), 0.f);
    A1.w = fmaxf(__fadd_rn(p1.w, __fmul_rn(be, g1.w)), 0.f);
    a4[i]  = A0;
    a4[i2] = A1;
    // compaction + hist, quad 0
    {
      unsigned u0 = __float_as_uint(A0.x), u1 = __float_as_uint(A0.y);
      unsigned u2 = __float_as_uint(A0.z), u3 = __float_as_uint(A0.w);
      bool c0 = (A0.x > 0.f) && ((u0 >> 20) >= bT0);
      bool c1 = (A0.y > 0.f) && ((u1 >> 20) >= bT0);
      bool c2 = (A0.z > 0.f) && ((u2 >> 20) >= bT0);
      bool c3 = (A0.w > 0.f) && ((u3 >> 20) >= bT0);
      unsigned long long m0 = __ballot(c0), m1 = __ballot(c1);
      unsigned long long m2 = __ballot(c2), m3 = __ballot(c3);
      unsigned n0 = __popcll(m0), n1 = __popcll(m1), n2 = __popcll(m2), n3 = __popcll(m3);
      unsigned tot = n0 + n1 + n2 + n3;
      if (tot) {
        unsigned base = 0;
        if (lane == 0) base = atomicAdd(&lcnt, tot);
        base = (unsigned)__shfl((int)base, 0);
        unsigned i0 = base + __popcll(m0 & lm_lt);
        unsigned i1 = base + n0 + __popcll(m1 & lm_lt);
        unsigned i2a = base + n0 + n1 + __popcll(m2 & lm_lt);
        unsigned i3 = base + n0 + n1 + n2 + __popcll(m3 & lm_lt);
        if (c0 && i0 < CBUF_CAP) cbuf[i0] = A0.x;
        if (c1 && i1 < CBUF_CAP) cbuf[i1] = A0.y;
        if (c2 && i2a < CBUF_CAP) cbuf[i2a] = A0.z;
        if (c3 && i3 < CBUF_CAP) cbuf[i3] = A0.w;
        if (c0) atomicAdd(&lh[u0 >> 20], 1u);
        if (c1) atomicAdd(&lh[u1 >> 20], 1u);
        if (c2) atomicAdd(&lh[u2 >> 20], 1u);
        if (c3) atomicAdd(&lh[u3 >> 20], 1u);
      }
    }
    // compaction + hist, quad 1
    {
      unsigned u0 = __float_as_uint(A1.x), u1 = __float_as_uint(A1.y);
      unsigned u2 = __float_as_uint(A1.z), u3 = __float_as_uint(A1.w);
      bool c0 = (A1.x > 0.f) && ((u0 >> 20) >= bT0);
      bool c1 = (A1.y > 0.f) && ((u1 >> 20) >= bT0);
      bool c2 = (A1.z > 0.f) && ((u2 >> 20) >= bT0);
      bool c3 = (A1.w > 0.f) && ((u3 >> 20) >= bT0);
      unsigned long long m0 = __ballot(c0), m1 = __ballot(c1);
      unsigned long long m2 = __ballot(c2), m3 = __ballot(c3);
      unsigned n0 = __popcll(m0), n1 = __popcll(m1), n2 = __popcll(m2), n3 = __popcll(m3);
      unsigned tot = n0 + n1 + n2 + n3;
      if (tot) {
        unsigned base = 0;
        if (lane == 0) base = atomicAdd(&lcnt, tot);
        base = (unsigned)__shfl((int)base, 0);
        unsigned i0 = base + __popcll(m0 & lm_lt);
        unsigned i1 = base + n0 + __popcll(m1 & lm_lt);
        unsigned i2a = base + n0 + n1 + __popcll(m2 & lm_lt);
        unsigned i3 = base + n0 + n1 + n2 + __popcll(m3 & lm_lt);
        if (c0 && i0 < CBUF_CAP) cbuf[i0] = A1.x;
        if (c1 && i1 < CBUF_CAP) cbuf[i1] = A1.y;
        if (c2 && i2a < CBUF_CAP) cbuf[i2a] = A1.z;
        if (c3 && i3 < CBUF_CAP) cbuf[i3] = A1.w;
        if (c0) atomicAdd(&lh[u0 >> 20], 1u);
        if (c1) atomicAdd(&lh[u1 >> 20], 1u);
        if (c2) atomicAdd(&lh[u2 >> 20], 1u);
        if (c3) atomicAdd(&lh[u3 >> 20], 1u);
      }
    }
  }
  __syncthreads();
  if (threadIdx.x == 0) {
    unsigned n = lcnt;
    if (n > CBUF_CAP) { atomicOr(&flags[b], 2u); n = CBUF_CAP; }
    unsigned gb = atomicAdd(&gcnt[b * 32], n);
    if (gb + n > CAND_CAP) atomicOr(&flags[b], 2u);
    gbase = gb;
  }
  __syncthreads();
  {
    float* candb = cand + ((size_t)b * CAND_CAP);
    const unsigned n = (lcnt > CBUF_CAP) ? CBUF_CAP : lcnt;
    const unsigned gb = gbase;
    for (unsigned i = threadIdx.x; i < n; i += 256) {
      unsigned d = gb + i;
      if (d < CAND_CAP) candb[d] = cbuf[i];
    }
  }
  for (int i = threadIdx.x; i < 2048; i += 256) {
    unsigned v = lh[i];
    if (v) atomicAdd(&ghist[(b << 11) + i], v);
  }
}

// ---------------- K4a: check restricted-hist sufficiency ----------------
__global__ __launch_bounds__(256) void k4a_check(const unsigned* __restrict__ ghist,
                                                 unsigned* __restrict__ flags) {
  __shared__ unsigned red[256];
  int b = blockIdx.x, t = threadIdx.x;
  unsigned s = 0;
  for (int j = 0; j < 8; j++) s += ghist[(b << 11) + t * 8 + j];
  red[t] = s; __syncthreads();
  for (int off = 128; off; off >>= 1) { if (t < off) red[t] += red[t + off]; __syncthreads(); }
  if (t == 0 && red[0] < KSEL) atomicOr(&flags[b], 1u);
}

// ---------------- K3fb: fallback full histogram of bins < binT0 (early-exit) ----------------
__global__ __launch_bounds__(256) void k3fb(const float* __restrict__ acts,
                                            const unsigned* __restrict__ binT0,
                                            const unsigned* __restrict__ flags,
                                            unsigned* __restrict__ ghist) {
  const int b = blockIdx.z;
  if ((flags[b] & 1u) == 0u) return;
  __shared__ unsigned lh[8192];
  const unsigned bT0 = binT0[b];
  const unsigned sub = threadIdx.x & 3;
  for (int i = threadIdx.x; i < 8192; i += 256) lh[i] = 0u;
  __syncthreads();
  const float4* a4 = (const float4*)(acts + ((size_t)b << 23));
  const int per4 = 1 << 21;
  for (int i = blockIdx.x * 256 + threadIdx.x; i < per4; i += gridDim.x * 256) {
    float4 a = a4[i];
    unsigned u;
    u = __float_as_uint(a.x);
    if (a.x > 0.f && (u >> 20) < bT0) atomicAdd(&lh[((u >> 20) << 2) | sub], 1u);
    u = __float_as_uint(a.y);
    if (a.y > 0.f && (u >> 20) < bT0) atomicAdd(&lh[((u >> 20) << 2) | sub], 1u);
    u = __float_as_uint(a.z);
    if (a.z > 0.f && (u >> 20) < bT0) atomicAdd(&lh[((u >> 20) << 2) | sub], 1u);
    u = __float_as_uint(a.w);
    if (a.w > 0.f && (u >> 20) < bT0) atomicAdd(&lh[((u >> 20) << 2) | sub], 1u);
  }
  __syncthreads();
  for (int i = threadIdx.x; i < 2048; i += 256) {
    unsigned v = lh[4 * i] + lh[4 * i + 1] + lh[4 * i + 2] + lh[4 * i + 3];
    if (v) atomicAdd(&ghist[(b << 11) + i], v);
  }
}

// ---------------- K4: pick coarse bin + remaining count ----------------
__global__ __launch_bounds__(256) void k4_coarse(const unsigned* __restrict__ ghist,
                                                 int* __restrict__ c1v,
                                                 int* __restrict__ remv,
                                                 float* __restrict__ kth) {
  __shared__ unsigned h[2048];
  __shared__ unsigned csum[256];
  int b = blockIdx.x, t = threadIdx.x;
  for (int i = t; i < 2048; i += 256) h[i] = ghist[(b << 11) + i];
  __syncthreads();
  unsigned cs = 0;
  for (int j = 0; j < 8; j++) cs += h[t * 8 + j];
  csum[t] = cs; __syncthreads();
  unsigned suf = 0;
  for (int tt = t + 1; tt < 256; tt++) suf += csum[tt];
  if (suf < KSEL && suf + cs >= KSEL) {
    unsigned cum = suf;
    for (int j = 7; j >= 0; j--) {
      unsigned hv = h[t * 8 + j];
      cum += hv;
      if (cum >= KSEL) { c1v[b] = t * 8 + j; remv[b] = (int)(KSEL - (cum - hv)); break; }
    }
  }
  if (t == 0) {
    unsigned tot = 0;
    for (int tt = 0; tt < 256; tt++) tot += csum[tt];
    if (tot < KSEL) { c1v[b] = -1; kth[b] = 0.f; }
  }
}

// ---------------- K5m: mid histogram (bits 19:10) within c1 ----------------
__global__ __launch_bounds__(256) void k5m(const float* __restrict__ acts,
                                           const float* __restrict__ cand,
                                           const unsigned* __restrict__ gcnt,
                                           const unsigned* __restrict__ flags,
                                           const int* __restrict__ c1v,
                                           unsigned* __restrict__ mid) {
  const int b = blockIdx.z;
  const int c1 = c1v[b];
  __shared__ unsigned lm[1024];
  for (int i = threadIdx.x; i < 1024; i += 256) lm[i] = 0u;
  __syncthreads();
  if (c1 >= 0) {
    const unsigned c1u = (unsigned)c1;
    if (flags[b] == 0u) {
      const float* candb = cand + ((size_t)b * CAND_CAP);
      const unsigned n = gcnt[b * 32];
      for (unsigned i = blockIdx.x * 256 + threadIdx.x; i < n; i += gridDim.x * 256) {
        unsigned u = __float_as_uint(candb[i]);
        if ((u >> 20) == c1u) atomicAdd(&lm[(u >> 10) & 0x3FFu], 1u);
      }
    } else {
      const float4* a4 = (const float4*)(acts + ((size_t)b << 23));
      for (int i = blockIdx.x * 256 + threadIdx.x; i < (1 << 21); i += gridDim.x * 256) {
        float4 a = a4[i];
        unsigned u;
        u = __float_as_uint(a.x);
        if (a.x > 0.f && (u >> 20) == c1u) atomicAdd(&lm[(u >> 10) & 0x3FFu], 1u);
        u = __float_as_uint(a.y);
        if (a.y > 0.f && (u >> 20) == c1u) atomicAdd(&lm[(u >> 10) & 0x3FFu], 1u);
        u = __float_as_uint(a.z);
        if (a.z > 0.f && (u >> 20) == c1u) atomicAdd(&lm[(u >> 10) & 0x3FFu], 1u);
        u = __float_as_uint(a.w);
        if (a.w > 0.f && (u >> 20) == c1u) atomicAdd(&lm[(u >> 10) & 0x3FFu], 1u);
      }
    }
  }
  __syncthreads();
  for (int i = threadIdx.x; i < 1024; i += 256) {
    unsigned v = lm[i];
    if (v) atomicAdd(&mid[(b << 10) + i], v);
  }
}

// ---------------- K6a: pick c2 + rem2 ----------------
__global__ __launch_bounds__(256) void k6a(const unsigned* __restrict__ mid,
                                           const int* __restrict__ c1v,
                                           const int* __restrict__ remv,
                                           int* __restrict__ c2v,
                                           int* __restrict__ rem2v) {
  int b = blockIdx.x, t = threadIdx.x;
  if (c1v[b] < 0) return;
  __shared__ unsigned h[1024];
  __shared__ unsigned csum[256];
  for (int i = t; i < 1024; i += 256) h[i] = mid[(b << 10) + i];
  __syncthreads();
  unsigned cs = 0;
  for (int j = 0; j < 4; j++) cs += h[t * 4 + j];
  csum[t] = cs; __syncthreads();
  unsigned suf = 0;
  for (int tt = t + 1; tt < 256; tt++) suf += csum[tt];
  unsigned R = (unsigned)remv[b];
  if (suf < R && suf + cs >= R) {
    unsigned cum = suf;
    for (int j = 3; j >= 0; j--) {
      unsigned hv = h[t * 4 + j];
      cum += hv;
      if (cum >= R) { c2v[b] = t * 4 + j; rem2v[b] = (int)(R - (cum - hv)); break; }
    }
  }
}

// ---------------- K5l: low histogram (bits 9:0) within (c1,c2) ----------------
__global__ __launch_bounds__(256) void k5l(const float* __restrict__ acts,
                                           const float* __restrict__ cand,
                                           const unsigned* __restrict__ gcnt,
                                           const unsigned* __restrict__ flags,
                                           const int* __restrict__ c1v,
                                           const int* __restrict__ c2v,
                                           unsigned* __restrict__ low) {
  const int b = blockIdx.z;
  const int c1 = c1v[b];
  __shared__ unsigned lm[1024];
  for (int i = threadIdx.x; i < 1024; i += 256) lm[i] = 0u;
  __syncthreads();
  if (c1 >= 0) {
    const unsigned key = ((unsigned)c1 << 10) | (unsigned)c2v[b];   // compare vs u>>10
    if (flags[b] == 0u) {
      const float* candb = cand + ((size_t)b * CAND_CAP);
      const unsigned n = gcnt[b * 32];
      for (unsigned i = blockIdx.x * 256 + threadIdx.x; i < n; i += gridDim.x * 256) {
        unsigned u = __float_as_uint(candb[i]);
        if ((u >> 10) == key) atomicAdd(&lm[u & 0x3FFu], 1u);
      }
    } else {
      const float4* a4 = (const float4*)(acts + ((size_t)b << 23));
      for (int i = blockIdx.x * 256 + threadIdx.x; i < (1 << 21); i += gridDim.x * 256) {
        float4 a = a4[i];
        unsigned u;
        u = __float_as_uint(a.x);
        if (a.x > 0.f && (u >> 10) == key) atomicAdd(&lm[u & 0x3FFu], 1u);
        u = __float_as_uint(a.y);
        if (a.y > 0.f && (u >> 10) == key) atomicAdd(&lm[u & 0x3FFu], 1u);
        u = __float_as_uint(a.z);
        if (a.z > 0.f && (u >> 10) == key) atomicAdd(&lm[u & 0x3FFu], 1u);
        u = __float_as_uint(a.w);
        if (a.w > 0.f && (u >> 10) == key) atomicAdd(&lm[u & 0x3FFu], 1u);
      }
    }
  }
  __syncthreads();
  for (int i = threadIdx.x; i < 1024; i += 256) {
    unsigned v = lm[i];
    if (v) atomicAdd(&low[(b << 10) + i], v);
  }
}

// ---------------- K6b: exact kth value ----------------
__global__ __launch_bounds__(256) void k6b(const unsigned* __restrict__ low,
                                           const int* __restrict__ c1v,
                                           const int* __restrict__ c2v,
                                           const int* __restrict__ rem2v,
                                           float* __restrict__ kth) {
  int b = blockIdx.x, t = threadIdx.x;
  int c1 = c1v[b];
  if (c1 < 0) return;
  __shared__ unsigned h[1024];
  __shared__ unsigned csum[256];
  for (int i = t; i < 1024; i += 256) h[i] = low[(b << 10) + i];
  __syncthreads();
  unsigned cs = 0;
  for (int j = 0; j < 4; j++) cs += h[t * 4 + j];
  csum[t] = cs; __syncthreads();
  unsigned suf = 0;
  for (int tt = t + 1; tt < 256; tt++) suf += csum[tt];
  unsigned R2 = (unsigned)rem2v[b];
  if (suf < R2 && suf + cs >= R2) {
    unsigned cum = suf;
    for (int j = 3; j >= 0; j--) {
      unsigned hv = h[t * 4 + j];
      cum += hv;
      if (cum >= R2) {
        unsigned bits = ((unsigned)c1 << 20) | ((unsigned)c2v[b] << 10) | (unsigned)(t * 4 + j);
        kth[b] = __uint_as_float(bits);
        break;
      }
    }
  }
}

// ---------------- K7g: mask + sparse write (NT) + decode GEMM (bf16 LDS, 8x8, kc=8, bf16 partials) ----------------
__global__ __launch_bounds__(256, 4) void k7g_decode(float* __restrict__ acts,
                                                     const unsigned short* __restrict__ wdb,
                                                     const float* __restrict__ kthv,
                                                     unsigned short* __restrict__ pdec) {
  __shared__ unsigned xsl[64 * 128];   // [o][p-pair] 32KB
  __shared__ unsigned wtl[64 * 32];    // [o][c-pair] 8KB
  const int t = threadIdx.x;
  const int pt = blockIdx.x;           // 0..15
  const int kc = blockIdx.y;           // 0..7
  const int b  = blockIdx.z;
  const int p0 = pt << 8;
  const float kth = kthv[b];
  const int cg = t >> 5;               // 0..7 -> c0 = cg*8
  const int pg = t & 31;               // p-group -> p = p0 + pg*8
  const int ob0 = kc * 256;

  float acc[8][8];
  #pragma unroll
  for (int i = 0; i < 8; i++)
    #pragma unroll
    for (int j = 0; j < 8; j++) acc[i][j] = 0.f;

  for (int tile = 0; tile < 4; ++tile) {
    __syncthreads();
    #pragma unroll
    for (int k = 0; k < 8; ++k) {
      const int ol = 8 * k + (t >> 5);
      float* ap = acts + (((size_t)(b * HCH + ob0 + tile * 64 + ol)) << 12) + p0 + ((t & 31) << 3);
      float4 a0 = ((const float4*)ap)[0];
      float4 a1 = ((const float4*)ap)[1];
      f4 s0, s1;
      s0.x = (a0.x >= kth) ? a0.x : 0.f;  s0.y = (a0.y >= kth) ? a0.y : 0.f;
      s0.z = (a0.z >= kth) ? a0.z : 0.f;  s0.w = (a0.w >= kth) ? a0.w : 0.f;
      s1.x = (a1.x >= kth) ? a1.x : 0.f;  s1.y = (a1.y >= kth) ? a1.y : 0.f;
      s1.z = (a1.z >= kth) ? a1.z : 0.f;  s1.w = (a1.w >= kth) ? a1.w : 0.f;
      __builtin_nontemporal_store(s0, (f4*)ap);        // final output, never re-read
      __builtin_nontemporal_store(s1, (f4*)ap + 1);
      uint4 pk;
      pk.x = bf16r(s0.x) | (bf16r(s0.y) << 16);
      pk.y = bf16r(s0.z) | (bf16r(s0.w) << 16);
      pk.z = bf16r(s1.x) | (bf16r(s1.y) << 16);
      pk.w = bf16r(s1.z) | (bf16r(s1.w) << 16);
      *(uint4*)&xsl[1024 * k + 4 * t] = pk;
    }
    #pragma unroll
    for (int k = 0; k < 2; ++k) {
      const int ol = 32 * k + (t >> 3);
      const uint4 w = *(const uint4*)(wdb + (((size_t)(ob0 + tile * 64 + ol)) << 6) + ((t & 7) << 3));
      *(uint4*)&wtl[1024 * k + 4 * t] = w;
    }
    __syncthreads();
    #pragma unroll 8
    for (int cc = 0; cc < 64; ++cc) {
      uint4 xv = *(const uint4*)&xsl[cc * 128 + pg * 4];
      uint4 wv = *(const uint4*)&wtl[cc * 32 + cg * 4];
      float xp[8], wf[8];
      xp[0] = __uint_as_float(xv.x << 16); xp[1] = __uint_as_float(xv.x & 0xffff0000u);
      xp[2] = __uint_as_float(xv.y << 16); xp[3] = __uint_as_float(xv.y & 0xffff0000u);
      xp[4] = __uint_as_float(xv.z << 16); xp[5] = __uint_as_float(xv.z & 0xffff0000u);
      xp[6] = __uint_as_float(xv.w << 16); xp[7] = __uint_as_float(xv.w & 0xffff0000u);
      wf[0] = __uint_as_float(wv.x << 16); wf[1] = __uint_as_float(wv.x & 0xffff0000u);
      wf[2] = __uint_as_float(wv.y << 16); wf[3] = __uint_as_float(wv.y & 0xffff0000u);
      wf[4] = __uint_as_float(wv.z << 16); wf[5] = __uint_as_float(wv.z & 0xffff0000u);
      wf[6] = __uint_as_float(wv.w << 16); wf[7] = __uint_as_float(wv.w & 0xffff0000u);
      #pragma unroll
      for (int i = 0; i < 8; i++)
        #pragma unroll
        for (int j = 0; j < 8; j++)
          acc[i][j] = fmaf(wf[i], xp[j], acc[i][j]);
    }
  }

  // write bf16 partial tile to slot kc (each address written exactly once)
  unsigned short* pb = pdec + (size_t)kc * RECON_N + (((size_t)(b * NC)) << 12) + p0 + pg * 8;
  #pragma unroll
  for (int i = 0; i < 8; ++i) {
    unsigned short* pr = pb + ((size_t)(cg * 8 + i) << 12);
    uint4 w;
    w.x = bf16r(acc[i][0]) | (bf16r(acc[i][1]) << 16);
    w.y = bf16r(acc[i][2]) | (bf16r(acc[i][3]) << 16);
    w.z = bf16r(acc[i][4]) | (bf16r(acc[i][5]) << 16);
    w.w = bf16r(acc[i][6]) | (bf16r(acc[i][7]) << 16);
    *(uint4*)pr = w;
  }
}

// ---------------- K8: recon = sum of 8 bf16 partial slots + b_dec (NT store) ----------------
__global__ __launch_bounds__(256) void k8_add(const unsigned short* __restrict__ pdec,
                                              const float* __restrict__ b_dec,
                                              float* __restrict__ recon) {
  const int i = blockIdx.x * 256 + threadIdx.x;   // over RECON_N/4 groups of 4
  if (i < (RECON_N / 4)) {
    const uint2* ps = (const uint2*)pdec;          // 4 bf16 per uint2
    float r0 = 0.f, r1 = 0.f, r2 = 0.f, r3 = 0.f;
    #pragma unroll
    for (int s = 0; s < 8; ++s) {
      uint2 v = ps[(size_t)s * (RECON_N / 4) + i];
      r0 += __uint_as_float(v.x << 16);
      r1 += __uint_as_float(v.x & 0xffff0000u);
      r2 += __uint_as_float(v.y << 16);
      r3 += __uint_as_float(v.y & 0xffff0000u);
    }
    const float bd = b_dec[(i >> 10) & 63];
    f4 r;
    r.x = r0 + bd; r.y = r1 + bd; r.z = r2 + bd; r.w = r3 + bd;
    __builtin_nontemporal_store(r, (f4*)recon + i);
  }
}

extern "C" void kernel_launch(void* const* d_in, const int* in_sizes, int n_in,
                              void* d_out, int out_size, void* d_ws, size_t ws_size,
                              hipStream_t stream) {
  const float* x     = (const float*)d_in[0];
  const float* W     = (const float*)d_in[1];
  const float* b_enc = (const float*)d_in[2];
  const float* b_dec = (const float*)d_in[3];
  const float* gum   = (const float*)d_in[4];
  float* recon  = (float*)d_out;
  float* sparse = recon + RECON_N;   // pre/acts scratch

  char* ws = (char*)d_ws;
  float*    cand  = (float*)(ws + WS_CAND);
  unsigned short* pdec = (unsigned short*)(ws + WS_CAND);  // reuse after k6b (no zeroing needed)
  unsigned short* wdb = (unsigned short*)(ws + WS_WD);
  unsigned* ghist = (unsigned*)(ws + WS_GHIST);
  unsigned* mid   = (unsigned*)(ws + WS_MID);
  unsigned* low   = (unsigned*)(ws + WS_LOW);
  double*   part  = (double*)(ws + WS_PART);
  float*    normv = (float*)(ws + WS_NORM);
  float*    beta  = (float*)(ws + WS_BETA);
  unsigned* binT0 = (unsigned*)(ws + WS_BINT0);
  int*      c1v   = (int*)(ws + WS_C1);
  int*      remv  = (int*)(ws + WS_REM);
  int*      c2v   = (int*)(ws + WS_C2);
  int*      rem2v = (int*)(ws + WS_REM2);
  float*    kth   = (float*)(ws + WS_KTH);
  unsigned* flags = (unsigned*)(ws + WS_FLAGS);
  unsigned* gcnt  = (unsigned*)(ws + WS_GCNT);

  hipMemsetAsync(ws + WS_GHIST, 0, 131072, stream);    // ghist+mid+low
  hipMemsetAsync(ws + WS_FLAGS, 0, 1152, stream);      // flags + padded gcnt

  k0a_norm  <<<64, 256, 0, stream>>>(W, normv);
  k0b_wd    <<<512, 256, 0, stream>>>(W, normv, wdb);
  k1_encode <<<dim3(32, 16, NB), 256, 0, stream>>>(x, W, b_enc, b_dec, sparse, part);
  k2_beta   <<<NB, 256, 0, stream>>>(part, beta, binT0);
  k3_acts   <<<dim3(1024, 1, NB), 256, 0, stream>>>(sparse, gum, beta, binT0, ghist, cand, gcnt, flags);
  k4a_check <<<NB, 256, 0, stream>>>(ghist, flags);
  k3fb      <<<dim3(1024, 1, NB), 256, 0, stream>>>(sparse, binT0, flags, ghist);
  k4_coarse <<<NB, 256, 0, stream>>>(ghist, c1v, remv, kth);
  k5m       <<<dim3(256, 1, NB), 256, 0, stream>>>(sparse, cand, gcnt, flags, c1v, mid);
  k6a       <<<NB, 256, 0, stream>>>(mid, c1v, remv, c2v, rem2v);
  k5l       <<<dim3(256, 1, NB), 256, 0, stream>>>(sparse, cand, gcnt, flags, c1v, c2v, low);
  k6b       <<<NB, 256, 0, stream>>>(low, c1v, c2v, rem2v, kth);
  k7g_decode<<<dim3(16, 8, NB), 256, 0, stream>>>(sparse, wdb, kth, pdec);
  k8_add    <<<RECON_N / 4 / 256, 256, 0, stream>>>(pdec, b_dec, recon);
}